// Round 1
// 244.949 us; speedup vs baseline: 1.1582x; 1.1582x over previous
//
#include <hip/hip_runtime.h>
#include <stdint.h>

typedef uint16_t u16;
typedef short s16x8 __attribute__((ext_vector_type(8)));
typedef float f32x4 __attribute__((ext_vector_type(4)));
typedef unsigned short u16x4 __attribute__((ext_vector_type(4)));
typedef uint32_t u32;
typedef u32 u32x2 __attribute__((ext_vector_type(2)));

#define MFMA16(a,b,c) __builtin_amdgcn_mfma_f32_16x16x32_bf16((a),(b),(c),0,0,0)
#define QSCALE 0.18033688011112042f   // 0.125 * log2(e)

__device__ __forceinline__ float b2f(u16 b){
  union { u32 u; float f; } v; v.u = ((u32)b)<<16; return v.f;
}
__device__ __forceinline__ u16 f2b(float f){
  union { float f; u32 u; } v; v.f = f;
  return (u16)((v.u + 0x7fffu + ((v.u>>16)&1u))>>16);
}
__device__ __forceinline__ u32 fbits(float f){
  union { float f; u32 u; } v; v.f = f; return v.u;
}
__device__ __forceinline__ float trunc_bf(float f){
  union { u32 u; float f; } v; v.u = fbits(f) & 0xffff0000u; return v.f;
}
__device__ __forceinline__ void load_lds_16B(const void* g, void* l){
  __builtin_amdgcn_global_load_lds((const __attribute__((address_space(1))) void*)g,
                                   (__attribute__((address_space(3))) void*)l, 16, 0, 0);
}

// ---------------- fp32 -> bf16 bulk convert (W matrices only) ----------------
__global__ __launch_bounds__(256) void convert_kernel(
    const float* __restrict__ W0, const float* __restrict__ W1,
    const float* __restrict__ W2, const float* __restrict__ W3,
    u16* __restrict__ Wb)
{
  const int y = blockIdx.y;
  const float* src = (y==0)?W0:(y==1)?W1:(y==2)?W2:W3;
  u16* dst = Wb + (size_t)y*1048576;
  const int g = blockIdx.x*256 + threadIdx.x;
#pragma unroll
  for (int t=0;t<4;t++){
    const int i4 = g + t*65536;
    const f32x4 v = *(const f32x4*)(src + (size_t)i4*4);
    u16x4 o;
#pragma unroll
    for (int j=0;j<4;j++) o[j] = f2b(v[j]);
    *(u16x4*)(dst + (size_t)i4*4) = o;
  }
}

// ---------------- LoRA t = X @ A^T for up to 3 matrices in one x-pass --------
// grid (1024), block 256. Wave w: row blockIdx.x*4+w. XF32: also emits xb.
template<bool XF32, int NMAT>
__global__ __launch_bounds__(256) void lora_t_kernel(
    const void* __restrict__ Xv,
    const float* __restrict__ A0, const float* __restrict__ A1, const float* __restrict__ A2,
    float* __restrict__ T0, float* __restrict__ T1, float* __restrict__ T2,
    u16* __restrict__ xb)
{
  const int wid = threadIdx.x>>6, lane = threadIdx.x&63;
  const int m = blockIdx.x*4 + wid;

  float xf[16];
  if (XF32){
    const float* xp = (const float*)Xv + (size_t)m*1024 + lane*16;
#pragma unroll
    for (int q=0;q<4;q++){
      const f32x4 v = *(const f32x4*)(xp + q*4);
#pragma unroll
      for (int j=0;j<4;j++) xf[q*4+j] = v[j];
    }
    u16* xbp = xb + (size_t)m*1024 + lane*16;
#pragma unroll
    for (int q=0;q<4;q++){
      u16x4 o;
#pragma unroll
      for (int j=0;j<4;j++) o[j] = f2b(xf[q*4+j]);
      *(u16x4*)(xbp + q*4) = o;
    }
  } else {
    const u16* xp = (const u16*)Xv + (size_t)m*1024 + lane*16;
#pragma unroll
    for (int j=0;j<16;j++) xf[j] = b2f(xp[j]);
  }

#pragma unroll
  for (int mat=0; mat<NMAT; mat++){
    const float* A = (mat==0)?A0:(mat==1)?A1:A2;
    float* T = (mat==0)?T0:(mat==1)?T1:T2;
    float accv[8];
#pragma unroll
    for (int r=0;r<8;r++){
      const float* ap = A + r*1024 + lane*16;
      float s = 0.f;
#pragma unroll
      for (int q=0;q<4;q++){
        const f32x4 av = *(const f32x4*)(ap + q*4);
#pragma unroll
        for (int j=0;j<4;j++) s += xf[q*4+j]*av[j];
      }
      accv[r] = s;
    }
#pragma unroll
    for (int r=0;r<8;r++){
      float s = accv[r];
      s += __shfl_xor(s,1);  s += __shfl_xor(s,2);  s += __shfl_xor(s,4);
      s += __shfl_xor(s,8);  s += __shfl_xor(s,16); s += __shfl_xor(s,32);
      accv[r] = s;
    }
    if (lane==0){
#pragma unroll
      for (int r=0;r<8;r++) T[(size_t)m*8 + r] = accv[r];
    }
  }
}

// ---------------- fused QKV GEMM (m97-style; LoRA epilogue via K=8 MFMA) -----
// grid (24,32): proj = bx>>3 (0=Q,1=K,2=V), n0=(bx&7)*128, m0=by*128.
__global__ __launch_bounds__(256,2) void gemm_qkv_kernel(
    const u16* __restrict__ Xb, const u16* __restrict__ Wb,
    const float* __restrict__ bq, const float* __restrict__ bk, const float* __restrict__ bv,
    const float* __restrict__ tq, const float* __restrict__ tk, const float* __restrict__ tv,
    const float* __restrict__ Blq, const float* __restrict__ Blk, const float* __restrict__ Blv,
    u16* __restrict__ Qb, u16* __restrict__ Kb, u16* __restrict__ Vtb)
{
  __shared__ u16 At[128*32];
  __shared__ u16 Bt[128*32];
  const int tid = threadIdx.x;
  const int wid = tid>>6, lane = tid&63;
  const int quad = lane>>4, l16 = lane&15;
  const int wm = wid>>1, wn = wid&1;
  const int proj = blockIdx.x>>3;
  const int n0 = (blockIdx.x&7)<<7, m0 = blockIdx.y<<7;
  const u16* W = Wb + (size_t)proj*1048576;
  const float* bias = (proj==0)?bq:(proj==1)?bk:bv;
  const float* T    = (proj==0)?tq:(proj==1)?tk:tv;
  const float* Bl   = (proj==0)?Blq:(proj==1)?Blk:Blv;
  const float scale = (proj==0)?QSCALE:1.0f;

  f32x4 acc[4][4];
#pragma unroll
  for (int i=0;i<4;i++)
#pragma unroll
    for (int j=0;j<4;j++) acc[i][j] = f32x4{0.f,0.f,0.f,0.f};

  for (int k0=0;k0<1024;k0+=32){
#pragma unroll
    for (int p=0;p<2;p++){
      const int s = wid*128 + p*64 + lane;
      const int row = s>>2, c = s&3;
      load_lds_16B(Xb + (size_t)(m0+row)*1024 + k0 + c*8, At + (wid*128+p*64)*8);
      load_lds_16B(W  + (size_t)(n0+row)*1024 + k0 + c*8, Bt + (wid*128+p*64)*8);
    }
    __syncthreads();
    s16x8 af[4], bfr[4];
#pragma unroll
    for (int t=0;t<4;t++){
      const int r = wm*64 + t*16 + l16;
      af[t]  = *(const s16x8*)(At + r*32 + quad*8);
      const int c = wn*64 + t*16 + l16;
      bfr[t] = *(const s16x8*)(Bt + c*32 + quad*8);
    }
#pragma unroll
    for (int tm=0;tm<4;tm++)
#pragma unroll
      for (int tn=0;tn<4;tn++)
        acc[tm][tn] = MFMA16(af[tm], bfr[tn], acc[tm][tn]);
    __syncthreads();
  }

  // LoRA term via one K=8 (zero-padded to 32) MFMA per acc tile: quad0 holds k=0..7
  s16x8 tf[4], bfl[4];
#pragma unroll
  for (int t=0;t<4;t++){ tf[t] = s16x8{0,0,0,0,0,0,0,0}; bfl[t] = s16x8{0,0,0,0,0,0,0,0}; }
  if (quad==0){
#pragma unroll
    for (int tm=0;tm<4;tm++){
      const float* tp = T + (size_t)(m0 + wm*64 + tm*16 + l16)*8;
      const f32x4 a0 = *(const f32x4*)(tp);
      const f32x4 a1 = *(const f32x4*)(tp+4);
#pragma unroll
      for (int j=0;j<4;j++){ tf[tm][j] = (short)f2b(2.0f*a0[j]); tf[tm][4+j] = (short)f2b(2.0f*a1[j]); }
    }
#pragma unroll
    for (int tn=0;tn<4;tn++){
      const float* bp = Bl + (size_t)(n0 + wn*64 + tn*16 + l16)*8;
      const f32x4 b0 = *(const f32x4*)(bp);
      const f32x4 b1 = *(const f32x4*)(bp+4);
#pragma unroll
      for (int j=0;j<4;j++){ bfl[tn][j] = (short)f2b(b0[j]); bfl[tn][4+j] = (short)f2b(b1[j]); }
    }
  }
#pragma unroll
  for (int tm=0;tm<4;tm++)
#pragma unroll
    for (int tn=0;tn<4;tn++)
      acc[tm][tn] = MFMA16(tf[tm], bfl[tn], acc[tm][tn]);

#pragma unroll
  for (int tn=0;tn<4;tn++){
    const int n = n0 + wn*64 + tn*16 + l16;
    const float bn = bias[n];
#pragma unroll
    for (int tm=0;tm<4;tm++){
      const int mb = m0 + wm*64 + tm*16 + quad*4;
      if (proj==0){
#pragma unroll
        for (int rg=0;rg<4;rg++) Qb[(size_t)(mb+rg)*1024 + n] = f2b((acc[tm][tn][rg]+bn)*scale);
      } else if (proj==1){
#pragma unroll
        for (int rg=0;rg<4;rg++) Kb[(size_t)(mb+rg)*1024 + n] = f2b(acc[tm][tn][rg]+bn);
      } else {
        const int batch = mb>>11, sI = mb&2047;
        const int hh = n>>6, dd = n&63;
        u16x4 pk;
#pragma unroll
        for (int rg=0;rg<4;rg++) pk[rg] = f2b(acc[tm][tn][rg]+bn);
        *(u16x4*)(Vtb + (size_t)((batch*16+hh)*64+dd)*2048 + sI) = pk;
      }
    }
  }
}

// ---------------- O-proj GEMM: 128x64 tiles, fp32 out, MFMA LoRA epilogue ----
__global__ __launch_bounds__(256,2) void gemm_o_kernel(
    const u16* __restrict__ Xb, const u16* __restrict__ W,
    const float* __restrict__ bias, const float* __restrict__ T,
    const float* __restrict__ Bl, float* __restrict__ Out)
{
  __shared__ u16 At[128*32];
  __shared__ u16 Bt[64*32];
  const int tid = threadIdx.x;
  const int wid = tid>>6, lane = tid&63;
  const int quad = lane>>4, l16 = lane&15;
  const int wm = wid>>1, wn = wid&1;
  const int m0 = blockIdx.y<<7, n0 = blockIdx.x<<6;

  f32x4 acc[4][2];
#pragma unroll
  for (int i=0;i<4;i++)
#pragma unroll
    for (int j=0;j<2;j++) acc[i][j] = f32x4{0.f,0.f,0.f,0.f};

  for (int k0=0;k0<1024;k0+=32){
#pragma unroll
    for (int p=0;p<2;p++){
      const int s = wid*128 + p*64 + lane;
      const int row = s>>2, c = s&3;
      load_lds_16B(Xb + (size_t)(m0+row)*1024 + k0 + c*8, At + (wid*128+p*64)*8);
    }
    { const int s = wid*64 + lane;
      const int row = s>>2, c = s&3;
      load_lds_16B(W + (size_t)(n0+row)*1024 + k0 + c*8, Bt + (wid*64)*8); }
    __syncthreads();
    s16x8 af[4], bfr[2];
#pragma unroll
    for (int t=0;t<4;t++){
      const int r = wm*64 + t*16 + l16;
      af[t] = *(const s16x8*)(At + r*32 + quad*8);
    }
#pragma unroll
    for (int t=0;t<2;t++){
      const int c = wn*32 + t*16 + l16;
      bfr[t] = *(const s16x8*)(Bt + c*32 + quad*8);
    }
#pragma unroll
    for (int tm=0;tm<4;tm++)
#pragma unroll
      for (int tn=0;tn<2;tn++)
        acc[tm][tn] = MFMA16(af[tm], bfr[tn], acc[tm][tn]);
    __syncthreads();
  }

  s16x8 tf[4], bfl[2];
#pragma unroll
  for (int t=0;t<4;t++) tf[t] = s16x8{0,0,0,0,0,0,0,0};
#pragma unroll
  for (int t=0;t<2;t++) bfl[t] = s16x8{0,0,0,0,0,0,0,0};
  if (quad==0){
#pragma unroll
    for (int tm=0;tm<4;tm++){
      const float* tp = T + (size_t)(m0 + wm*64 + tm*16 + l16)*8;
      const f32x4 a0 = *(const f32x4*)(tp);
      const f32x4 a1 = *(const f32x4*)(tp+4);
#pragma unroll
      for (int j=0;j<4;j++){ tf[tm][j] = (short)f2b(2.0f*a0[j]); tf[tm][4+j] = (short)f2b(2.0f*a1[j]); }
    }
#pragma unroll
    for (int tn=0;tn<2;tn++){
      const float* bp = Bl + (size_t)(n0 + wn*32 + tn*16 + l16)*8;
      const f32x4 b0 = *(const f32x4*)(bp);
      const f32x4 b1 = *(const f32x4*)(bp+4);
#pragma unroll
      for (int j=0;j<4;j++){ bfl[tn][j] = (short)f2b(b0[j]); bfl[tn][4+j] = (short)f2b(b1[j]); }
    }
  }
#pragma unroll
  for (int tm=0;tm<4;tm++)
#pragma unroll
    for (int tn=0;tn<2;tn++)
      acc[tm][tn] = MFMA16(tf[tm], bfl[tn], acc[tm][tn]);

#pragma unroll
  for (int tn=0;tn<2;tn++){
    const int n = n0 + wn*32 + tn*16 + l16;
    const float bn = bias[n];
#pragma unroll
    for (int tm=0;tm<4;tm++){
      const int mb = m0 + wm*64 + tm*16 + quad*4;
#pragma unroll
      for (int rg=0;rg<4;rg++)
        Out[(size_t)(mb+rg)*1024 + n] = acc[tm][tn][rg] + bn;
    }
  }
}

// ---------------- MFMA flash attention: 128-q blocks, 32 q/wave, no-max ------
// grid (16,16,2) = 512 blocks. S^T = K·Q^T; softmax = direct exp2 (|S|<~6 by
// input distribution; overflow needs |S|>127). l = sum of TRUNCATED P (matches
// the bf16 P used in PV exactly -> unbiased).
// v2: separate Pt buffer (no Kt aliasing) -> mid-tile barrier GONE and
// exp2/pack/store fused per-tn into the QK^T loop (S live range 64 regs -> 8);
// register-prefetch double-buffer of K/V staging (T14); direct v_exp_f32;
// cross-quad l-reduction deferred to epilogue; setprio around PV MFMA cluster.
// LDS: Kt 18432 + Vtl 17408 + Pt 34816 = 70656 B -> 2 blocks/CU (grid=2/CU).
__global__ __launch_bounds__(256,2) void attn_kernel(
    const u16* __restrict__ Q, const u16* __restrict__ K,
    const u16* __restrict__ Vt, u16* __restrict__ Out)
{
  __shared__ u16 Kt[128*72];
  __shared__ u16 Vtl[64*136];
  __shared__ u16 Pt[128*136];
  const int tid = threadIdx.x;
  const int wid = tid>>6, lane = tid&63;
  const int quad = lane>>4, l16 = lane&15;
  const int q0 = blockIdx.x<<7;
  const int h = blockIdx.y, nb = blockIdx.z;
  const int qw = wid*32;                    // wave's 32 q-cols: qw + g*16 + l16

  s16x8 qf[2][2];
#pragma unroll
  for (int g=0;g<2;g++){
    const int row = q0 + qw + g*16 + l16;
#pragma unroll
    for (int dh=0;dh<2;dh++)
      qf[g][dh] = *(const s16x8*)(Q + (size_t)(nb*2048+row)*1024 + h*64 + dh*32 + quad*8);
  }
  f32x4 OT[2][4];                           // C: d = td*16+quad*4+rg, q-col = l16
  float lr[2] = {0.f, 0.f};                 // per-lane partial (quads combined at end)
#pragma unroll
  for (int g=0;g<2;g++)
#pragma unroll
    for (int td=0;td<4;td++) OT[g][td] = f32x4{0.f,0.f,0.f,0.f};

  // prefetch registers: tile staged global->reg here, reg->LDS at loop top
  s16x8 kreg[4], vreg[4];
#pragma unroll
  for (int p=0;p<4;p++){
    const int s = p*256 + tid;
    { const int row = s>>3, c = s&7;
      kreg[p] = *(const s16x8*)(K + (size_t)(nb*2048+row)*1024 + h*64 + c*8); }
    { const int row = s>>4, c = s&15;
      vreg[p] = *(const s16x8*)(Vt + (size_t)((nb*16+h)*64+row)*2048 + c*8); }
  }

  for (int kt=0; kt<2048; kt+=128){
    // write previously-loaded tile to LDS
#pragma unroll
    for (int p=0;p<4;p++){
      const int s = p*256 + tid;
      { const int row = s>>3, c = s&7;
        *(s16x8*)(Kt + row*72 + c*8) = kreg[p]; }
      { const int row = s>>4, c = s&15;
        *(s16x8*)(Vtl + row*136 + c*8) = vreg[p]; }
    }
    __syncthreads();

    // issue next tile's global loads NOW; latency hides under this tile's math
    if (kt < 2048-128){
      const int kn = kt + 128;
#pragma unroll
      for (int p=0;p<4;p++){
        const int s = p*256 + tid;
        { const int row = s>>3, c = s&7;
          kreg[p] = *(const s16x8*)(K + (size_t)(nb*2048+kn+row)*1024 + h*64 + c*8); }
        { const int row = s>>4, c = s&15;
          vreg[p] = *(const s16x8*)(Vt + (size_t)((nb*16+h)*64+row)*2048 + kn + c*8); }
      }
    }

    // S^T = K·Q^T (QSCALE*log2e folded into Q) fused with exp2 + pack + Pt store.
    // Pt rows are wave-private -> no barrier between QK^T and PV.
#pragma unroll
    for (int tn=0;tn<8;tn++){
      const int key = tn*16 + l16;
      const s16x8 kf0 = *(const s16x8*)(Kt + key*72 + quad*8);
      const s16x8 kf1 = *(const s16x8*)(Kt + key*72 + 32 + quad*8);
#pragma unroll
      for (int g=0;g<2;g++){
        f32x4 z = f32x4{0.f,0.f,0.f,0.f};
        z = MFMA16(kf0, qf[g][0], z);
        z = MFMA16(kf1, qf[g][1], z);
        float p0 = __builtin_amdgcn_exp2f(z[0]);
        float p1 = __builtin_amdgcn_exp2f(z[1]);
        float p2 = __builtin_amdgcn_exp2f(z[2]);
        float p3 = __builtin_amdgcn_exp2f(z[3]);
        lr[g] += (trunc_bf(p0)+trunc_bf(p1)) + (trunc_bf(p2)+trunc_bf(p3));
        u32x2 pk;
        pk[0] = __builtin_amdgcn_perm(fbits(p1), fbits(p0), 0x07060302u);
        pk[1] = __builtin_amdgcn_perm(fbits(p3), fbits(p2), 0x07060302u);
        *(u32x2*)(Pt + (qw+g*16+l16)*136 + tn*16 + quad*4) = pk;
      }
    }

    // OT += V^T·P^T : vf shared across both q-groups
    __builtin_amdgcn_s_setprio(1);
#pragma unroll
    for (int kb=0;kb<4;kb++){
      s16x8 pf[2];
#pragma unroll
      for (int g=0;g<2;g++)
        pf[g] = *(const s16x8*)(Pt + (qw+g*16+l16)*136 + kb*32 + quad*8);
#pragma unroll
      for (int td=0;td<4;td++){
        const s16x8 vf = *(const s16x8*)(Vtl + (td*16+l16)*136 + kb*32 + quad*8);
#pragma unroll
        for (int g=0;g<2;g++)
          OT[g][td] = MFMA16(vf, pf[g], OT[g][td]);
      }
    }
    __builtin_amdgcn_s_setprio(0);
    __syncthreads();   // all waves done reading Kt/Vtl before next staging write
  }

  // epilogue: combine quad partials of l once, then scale + RNE pack
#pragma unroll
  for (int g=0;g<2;g++){
    float t = lr[g];
    t += __shfl_xor(t,16);
    t += __shfl_xor(t,32);
    const float linv = 1.0f / t;
    const int q = q0 + qw + g*16 + l16;
#pragma unroll
    for (int td=0;td<4;td++){
      u16x4 pk;
#pragma unroll
      for (int rg=0;rg<4;rg++) pk[rg] = f2b(OT[g][td][rg]*linv);
      *(u16x4*)(Out + (size_t)(nb*2048+q)*1024 + h*64 + td*16 + quad*4) = pk;
    }
  }
}

extern "C" void kernel_launch(void* const* d_in, const int* in_sizes, int n_in,
                              void* d_out, int out_size, void* d_ws, size_t ws_size,
                              hipStream_t stream)
{
  const float* x  = (const float*)d_in[0];
  const float* Wq = (const float*)d_in[1];  const float* bq = (const float*)d_in[2];
  const float* Aq = (const float*)d_in[3];  const float* Bq = (const float*)d_in[4];
  const float* Wk = (const float*)d_in[5];  const float* bk = (const float*)d_in[6];
  const float* Ak = (const float*)d_in[7];  const float* Bk = (const float*)d_in[8];
  const float* Wv = (const float*)d_in[9];  const float* bv = (const float*)d_in[10];
  const float* Av = (const float*)d_in[11]; const float* Bv = (const float*)d_in[12];
  const float* Wo = (const float*)d_in[13]; const float* bo = (const float*)d_in[14];
  const float* Ao = (const float*)d_in[15]; const float* Bo = (const float*)d_in[16];

  char* ws = (char*)d_ws;
  float* tq = (float*)(ws + 0);
  float* tk = (float*)(ws + 131072);
  float* tv = (float*)(ws + 262144);
  float* to = (float*)(ws + 393216);
  u16* xb  = (u16*)(ws + 524288);              // 8 MB; Ab aliases (xb dead after QKV)
  u16* Ab  = xb;
  u16* Wb  = (u16*)(ws + 524288 + 8388608);
  u16* Qb  = (u16*)(ws + 524288 + 2*8388608);
  u16* Kb  = (u16*)(ws + 524288 + 3*8388608);
  u16* Vtb = (u16*)(ws + 524288 + 4*8388608);

  lora_t_kernel<true,3><<<dim3(1024),256,0,stream>>>(x, Aq, Ak, Av, tq, tk, tv, xb);
  convert_kernel<<<dim3(256,4),256,0,stream>>>(Wq, Wk, Wv, Wo, Wb);
  gemm_qkv_kernel<<<dim3(24,32),256,0,stream>>>(xb, Wb, bq, bk, bv, tq, tk, tv,
                                                Bq, Bk, Bv, Qb, Kb, Vtb);
  attn_kernel<<<dim3(16,16,2),256,0,stream>>>(Qb, Kb, Vtb, Ab);
  lora_t_kernel<false,1><<<dim3(1024),256,0,stream>>>(Ab, Ao, Ao, Ao, to, to, to, nullptr);
  gemm_o_kernel<<<dim3(16,32),256,0,stream>>>(Ab, Wb + (size_t)3*1048576, bo, to, Bo,
                                              (float*)d_out);
}

// Round 3
// 242.708 us; speedup vs baseline: 1.1689x; 1.0092x over previous
//
#include <hip/hip_runtime.h>
#include <stdint.h>

typedef uint16_t u16;
typedef short s16x8 __attribute__((ext_vector_type(8)));
typedef float f32x4 __attribute__((ext_vector_type(4)));
typedef unsigned short u16x4 __attribute__((ext_vector_type(4)));
typedef uint32_t u32;
typedef u32 u32x2 __attribute__((ext_vector_type(2)));
typedef u32 u32x4 __attribute__((ext_vector_type(4)));

#define MFMA16(a,b,c) __builtin_amdgcn_mfma_f32_16x16x32_bf16((a),(b),(c),0,0,0)
#define QSCALE 0.18033688011112042f   // 0.125 * log2(e)

__device__ __forceinline__ float b2f(u16 b){
  union { u32 u; float f; } v; v.u = ((u32)b)<<16; return v.f;
}
__device__ __forceinline__ u16 f2b(float f){
  union { float f; u32 u; } v; v.f = f;
  return (u16)((v.u + 0x7fffu + ((v.u>>16)&1u))>>16);
}
__device__ __forceinline__ u32 fbits(float f){
  union { float f; u32 u; } v; v.f = f; return v.u;
}
__device__ __forceinline__ float trunc_bf(float f){
  union { u32 u; float f; } v; v.u = fbits(f) & 0xffff0000u; return v.f;
}
__device__ __forceinline__ void load_lds_16B(const void* g, void* l){
  __builtin_amdgcn_global_load_lds((const __attribute__((address_space(1))) void*)g,
                                   (__attribute__((address_space(3))) void*)l, 16, 0, 0);
}

// ---------------- merged LoRA t = X @ A^T  (+ optional W fp32->bf16 convert) -
// XF32 call: grid 2048. blocks [0,1024): lora rows (also emits xb);
//            blocks [1024,2048): convert W0..W3 -> Wb (independent, overlapped).
// !XF32 call: grid 1024, lora only.
template<bool XF32, int NMAT>
__global__ __launch_bounds__(256) void lora_conv_kernel(
    const void* __restrict__ Xv,
    const float* __restrict__ A0, const float* __restrict__ A1, const float* __restrict__ A2,
    float* __restrict__ T0, float* __restrict__ T1, float* __restrict__ T2,
    u16* __restrict__ xb,
    const float* __restrict__ W0, const float* __restrict__ W1,
    const float* __restrict__ W2, const float* __restrict__ W3,
    u16* __restrict__ Wb)
{
  if (XF32 && blockIdx.x >= 1024){
    const int cv = blockIdx.x - 1024;
    const int y = cv>>8;
    const float* src = (y==0)?W0:(y==1)?W1:(y==2)?W2:W3;
    u16* dst = Wb + (size_t)y*1048576;
    const int g = (cv&255)*256 + threadIdx.x;
#pragma unroll
    for (int t=0;t<4;t++){
      const int i4 = g + t*65536;
      const f32x4 v = *(const f32x4*)(src + (size_t)i4*4);
      u16x4 o;
#pragma unroll
      for (int j=0;j<4;j++) o[j] = f2b(v[j]);
      *(u16x4*)(dst + (size_t)i4*4) = o;
    }
    return;
  }

  const int wid = threadIdx.x>>6, lane = threadIdx.x&63;
  const int m = blockIdx.x*4 + wid;

  float xf[16];
  if (XF32){
    const float* xp = (const float*)Xv + (size_t)m*1024 + lane*16;
#pragma unroll
    for (int q=0;q<4;q++){
      const f32x4 v = *(const f32x4*)(xp + q*4);
#pragma unroll
      for (int j=0;j<4;j++) xf[q*4+j] = v[j];
    }
    u16* xbp = xb + (size_t)m*1024 + lane*16;
#pragma unroll
    for (int q=0;q<4;q++){
      u16x4 o;
#pragma unroll
      for (int j=0;j<4;j++) o[j] = f2b(xf[q*4+j]);
      *(u16x4*)(xbp + q*4) = o;
    }
  } else {
    const u16* xp = (const u16*)Xv + (size_t)m*1024 + lane*16;
#pragma unroll
    for (int j=0;j<16;j++) xf[j] = b2f(xp[j]);
  }

#pragma unroll
  for (int mat=0; mat<NMAT; mat++){
    const float* A = (mat==0)?A0:(mat==1)?A1:A2;
    float* T = (mat==0)?T0:(mat==1)?T1:T2;
    float accv[8];
#pragma unroll
    for (int r=0;r<8;r++){
      const float* ap = A + r*1024 + lane*16;
      float s = 0.f;
#pragma unroll
      for (int q=0;q<4;q++){
        const f32x4 av = *(const f32x4*)(ap + q*4);
#pragma unroll
        for (int j=0;j<4;j++) s += xf[q*4+j]*av[j];
      }
      accv[r] = s;
    }
#pragma unroll
    for (int r=0;r<8;r++){
      float s = accv[r];
      s += __shfl_xor(s,1);  s += __shfl_xor(s,2);  s += __shfl_xor(s,4);
      s += __shfl_xor(s,8);  s += __shfl_xor(s,16); s += __shfl_xor(s,32);
      accv[r] = s;
    }
    if (lane==0){
#pragma unroll
      for (int r=0;r<8;r++) T[(size_t)m*8 + r] = accv[r];
    }
  }
}

// ---------------- fused QKV GEMM (m97-style; LoRA epilogue via K=8 MFMA) -----
// grid (24,32): proj = bx>>3 (0=Q,1=K,2=V), n0=(bx&7)*128, m0=by*128.
__global__ __launch_bounds__(256,2) void gemm_qkv_kernel(
    const u16* __restrict__ Xb, const u16* __restrict__ Wb,
    const float* __restrict__ bq, const float* __restrict__ bk, const float* __restrict__ bv,
    const float* __restrict__ tq, const float* __restrict__ tk, const float* __restrict__ tv,
    const float* __restrict__ Blq, const float* __restrict__ Blk, const float* __restrict__ Blv,
    u16* __restrict__ Qb, u16* __restrict__ Kb, u16* __restrict__ Vtb)
{
  __shared__ u16 At[128*32];
  __shared__ u16 Bt[128*32];
  const int tid = threadIdx.x;
  const int wid = tid>>6, lane = tid&63;
  const int quad = lane>>4, l16 = lane&15;
  const int wm = wid>>1, wn = wid&1;
  const int proj = blockIdx.x>>3;
  const int n0 = (blockIdx.x&7)<<7, m0 = blockIdx.y<<7;
  const u16* W = Wb + (size_t)proj*1048576;
  const float* bias = (proj==0)?bq:(proj==1)?bk:bv;
  const float* T    = (proj==0)?tq:(proj==1)?tk:tv;
  const float* Bl   = (proj==0)?Blq:(proj==1)?Blk:Blv;
  const float scale = (proj==0)?QSCALE:1.0f;

  f32x4 acc[4][4];
#pragma unroll
  for (int i=0;i<4;i++)
#pragma unroll
    for (int j=0;j<4;j++) acc[i][j] = f32x4{0.f,0.f,0.f,0.f};

  for (int k0=0;k0<1024;k0+=32){
#pragma unroll
    for (int p=0;p<2;p++){
      const int s = wid*128 + p*64 + lane;
      const int row = s>>2, c = s&3;
      load_lds_16B(Xb + (size_t)(m0+row)*1024 + k0 + c*8, At + (wid*128+p*64)*8);
      load_lds_16B(W  + (size_t)(n0+row)*1024 + k0 + c*8, Bt + (wid*128+p*64)*8);
    }
    __syncthreads();
    s16x8 af[4], bfr[4];
#pragma unroll
    for (int t=0;t<4;t++){
      const int r = wm*64 + t*16 + l16;
      af[t]  = *(const s16x8*)(At + r*32 + quad*8);
      const int c = wn*64 + t*16 + l16;
      bfr[t] = *(const s16x8*)(Bt + c*32 + quad*8);
    }
#pragma unroll
    for (int tm=0;tm<4;tm++)
#pragma unroll
      for (int tn=0;tn<4;tn++)
        acc[tm][tn] = MFMA16(af[tm], bfr[tn], acc[tm][tn]);
    __syncthreads();
  }

  // LoRA term via one K=8 (zero-padded to 32) MFMA per acc tile: quad0 holds k=0..7
  s16x8 tf[4], bfl[4];
#pragma unroll
  for (int t=0;t<4;t++){ tf[t] = s16x8{0,0,0,0,0,0,0,0}; bfl[t] = s16x8{0,0,0,0,0,0,0,0}; }
  if (quad==0){
#pragma unroll
    for (int tm=0;tm<4;tm++){
      const float* tp = T + (size_t)(m0 + wm*64 + tm*16 + l16)*8;
      const f32x4 a0 = *(const f32x4*)(tp);
      const f32x4 a1 = *(const f32x4*)(tp+4);
#pragma unroll
      for (int j=0;j<4;j++){ tf[tm][j] = (short)f2b(2.0f*a0[j]); tf[tm][4+j] = (short)f2b(2.0f*a1[j]); }
    }
#pragma unroll
    for (int tn=0;tn<4;tn++){
      const float* bp = Bl + (size_t)(n0 + wn*64 + tn*16 + l16)*8;
      const f32x4 b0 = *(const f32x4*)(bp);
      const f32x4 b1 = *(const f32x4*)(bp+4);
#pragma unroll
      for (int j=0;j<4;j++){ bfl[tn][j] = (short)f2b(b0[j]); bfl[tn][4+j] = (short)f2b(b1[j]); }
    }
  }
#pragma unroll
  for (int tm=0;tm<4;tm++)
#pragma unroll
    for (int tn=0;tn<4;tn++)
      acc[tm][tn] = MFMA16(tf[tm], bfl[tn], acc[tm][tn]);

#pragma unroll
  for (int tn=0;tn<4;tn++){
    const int n = n0 + wn*64 + tn*16 + l16;
    const float bn = bias[n];
#pragma unroll
    for (int tm=0;tm<4;tm++){
      const int mb = m0 + wm*64 + tm*16 + quad*4;
      if (proj==0){
#pragma unroll
        for (int rg=0;rg<4;rg++) Qb[(size_t)(mb+rg)*1024 + n] = f2b((acc[tm][tn][rg]+bn)*scale);
      } else if (proj==1){
#pragma unroll
        for (int rg=0;rg<4;rg++) Kb[(size_t)(mb+rg)*1024 + n] = f2b(acc[tm][tn][rg]+bn);
      } else {
        const int batch = mb>>11, sI = mb&2047;
        const int hh = n>>6, dd = n&63;
        u16x4 pk;
#pragma unroll
        for (int rg=0;rg<4;rg++) pk[rg] = f2b(acc[tm][tn][rg]+bn);
        *(u16x4*)(Vtb + (size_t)((batch*16+hh)*64+dd)*2048 + sI) = pk;
      }
    }
  }
}

// ---------------- O-proj GEMM: 128x64 tiles, fp32 out, MFMA LoRA epilogue ----
__global__ __launch_bounds__(256,2) void gemm_o_kernel(
    const u16* __restrict__ Xb, const u16* __restrict__ W,
    const float* __restrict__ bias, const float* __restrict__ T,
    const float* __restrict__ Bl, float* __restrict__ Out)
{
  __shared__ u16 At[128*32];
  __shared__ u16 Bt[64*32];
  const int tid = threadIdx.x;
  const int wid = tid>>6, lane = tid&63;
  const int quad = lane>>4, l16 = lane&15;
  const int wm = wid>>1, wn = wid&1;
  const int m0 = blockIdx.y<<7, n0 = blockIdx.x<<6;

  f32x4 acc[4][2];
#pragma unroll
  for (int i=0;i<4;i++)
#pragma unroll
    for (int j=0;j<2;j++) acc[i][j] = f32x4{0.f,0.f,0.f,0.f};

  for (int k0=0;k0<1024;k0+=32){
#pragma unroll
    for (int p=0;p<2;p++){
      const int s = wid*128 + p*64 + lane;
      const int row = s>>2, c = s&3;
      load_lds_16B(Xb + (size_t)(m0+row)*1024 + k0 + c*8, At + (wid*128+p*64)*8);
    }
    { const int s = wid*64 + lane;
      const int row = s>>2, c = s&3;
      load_lds_16B(W + (size_t)(n0+row)*1024 + k0 + c*8, Bt + (wid*64)*8); }
    __syncthreads();
    s16x8 af[4], bfr[2];
#pragma unroll
    for (int t=0;t<4;t++){
      const int r = wm*64 + t*16 + l16;
      af[t] = *(const s16x8*)(At + r*32 + quad*8);
    }
#pragma unroll
    for (int t=0;t<2;t++){
      const int c = wn*32 + t*16 + l16;
      bfr[t] = *(const s16x8*)(Bt + c*32 + quad*8);
    }
#pragma unroll
    for (int tm=0;tm<4;tm++)
#pragma unroll
      for (int tn=0;tn<2;tn++)
        acc[tm][tn] = MFMA16(af[tm], bfr[tn], acc[tm][tn]);
    __syncthreads();
  }

  s16x8 tf[4], bfl[2];
#pragma unroll
  for (int t=0;t<4;t++) tf[t] = s16x8{0,0,0,0,0,0,0,0};
#pragma unroll
  for (int t=0;t<2;t++) bfl[t] = s16x8{0,0,0,0,0,0,0,0};
  if (quad==0){
#pragma unroll
    for (int tm=0;tm<4;tm++){
      const float* tp = T + (size_t)(m0 + wm*64 + tm*16 + l16)*8;
      const f32x4 a0 = *(const f32x4*)(tp);
      const f32x4 a1 = *(const f32x4*)(tp+4);
#pragma unroll
      for (int j=0;j<4;j++){ tf[tm][j] = (short)f2b(2.0f*a0[j]); tf[tm][4+j] = (short)f2b(2.0f*a1[j]); }
    }
#pragma unroll
    for (int tn=0;tn<2;tn++){
      const float* bp = Bl + (size_t)(n0 + wn*32 + tn*16 + l16)*8;
      const f32x4 b0 = *(const f32x4*)(bp);
      const f32x4 b1 = *(const f32x4*)(bp+4);
#pragma unroll
      for (int j=0;j<4;j++){ bfl[tn][j] = (short)f2b(b0[j]); bfl[tn][4+j] = (short)f2b(b1[j]); }
    }
  }
#pragma unroll
  for (int tm=0;tm<4;tm++)
#pragma unroll
    for (int tn=0;tn<2;tn++)
      acc[tm][tn] = MFMA16(tf[tm], bfl[tn], acc[tm][tn]);

#pragma unroll
  for (int tn=0;tn<2;tn++){
    const int n = n0 + wn*32 + tn*16 + l16;
    const float bn = bias[n];
#pragma unroll
    for (int tm=0;tm<4;tm++){
      const int mb = m0 + wm*64 + tm*16 + quad*4;
#pragma unroll
      for (int rg=0;rg<4;rg++)
        Out[(size_t)(mb+rg)*1024 + n] = acc[tm][tn][rg] + bn;
    }
  }
}

// ---------------- MFMA flash attention v3b -----------------------------------
// grid (16,16,2). S^T = K·Q^T; direct-exp2 softmax; l = sum of truncated P.
// v3b: in-register P quad-redistribution via __builtin_amdgcn_permlane{32,16}_swap
// (NOT inline asm: gfx950 needs a wait state between a VALU VGPR write and a
// v_permlane*_swap read of it; the compiler's hazard recognizer only inserts it
// for the builtin — opaque inline asm skipped it and read stale operands = R2 fail).
// Producer word layout (per kb, per g): ew/ow[h] = packed bf16 P for keys
// sel*16+quad*4+{2h,2h+1}; consumer B-frag word w needs keys quad*8+{2w,2w+1}.
// swap32(ew,ow) -> (x=(e0,e1,o0,o1), y=(e2,e3,o2,o3)); swap16(x,y) ->
// (word_even=(e0,e2,o0,o2), word_odd2=(e1,e3,o1,o3)) per h. LDS double-buffered
// K/V, one barrier/tile. LDS: 2*(128*72 + 64*136)*2B = 71680 B -> 2 blocks/CU.
__global__ __launch_bounds__(256,2) void attn_kernel(
    const u16* __restrict__ Q, const u16* __restrict__ K,
    const u16* __restrict__ Vt, u16* __restrict__ Out)
{
  __shared__ u16 KtB[2][128*72];
  __shared__ u16 VtB[2][64*136];
  const int tid = threadIdx.x;
  const int wid = tid>>6, lane = tid&63;
  const int quad = lane>>4, l16 = lane&15;
  const int q0 = blockIdx.x<<7;
  const int h = blockIdx.y, nb = blockIdx.z;
  const int qw = wid*32;                    // wave's 32 q-cols: qw + g*16 + l16

  s16x8 qf[2][2];
#pragma unroll
  for (int g=0;g<2;g++){
    const int row = q0 + qw + g*16 + l16;
#pragma unroll
    for (int dh=0;dh<2;dh++)
      qf[g][dh] = *(const s16x8*)(Q + (size_t)(nb*2048+row)*1024 + h*64 + dh*32 + quad*8);
  }
  f32x4 OT[2][4];                           // C: d = td*16+quad*4+rg, q-col = l16
  float lr[2] = {0.f, 0.f};
#pragma unroll
  for (int g=0;g<2;g++)
#pragma unroll
    for (int td=0;td<4;td++) OT[g][td] = f32x4{0.f,0.f,0.f,0.f};

  s16x8 kreg[4], vreg[4];
  auto LOADT = [&](int kn){
#pragma unroll
    for (int p=0;p<4;p++){
      const int s = p*256 + tid;
      kreg[p] = *(const s16x8*)(K + (size_t)(nb*2048+kn+(s>>3))*1024 + h*64 + (s&7)*8);
      vreg[p] = *(const s16x8*)(Vt + (size_t)((nb*16+h)*64+(s>>4))*2048 + kn + (s&15)*8);
    }
  };
  auto WRITET = [&](int b){
    u16* Ktb = KtB[b]; u16* Vtb = VtB[b];
#pragma unroll
    for (int p=0;p<4;p++){
      const int s = p*256 + tid;
      *(s16x8*)(Ktb + (s>>3)*72 + (s&7)*8) = kreg[p];
      *(s16x8*)(Vtb + (s>>4)*136 + (s&15)*8) = vreg[p];
    }
  };

  LOADT(0);
  WRITET(0);
  LOADT(128);
  __syncthreads();

  for (int t=0;t<16;t++){
    const int cur = t&1;
    if (t < 15) WRITET(cur^1);              // regs hold tile t+1; buf consumed at t-1
    if (t < 14) LOADT((t+2)*128);           // latency hides under this tile's math
    const u16* KtC = KtB[cur];
    const u16* VtC = VtB[cur];

#pragma unroll
    for (int kb=0;kb<4;kb++){
      u32 ew[2][2], ow[2][2];               // packed bf16 P words [g][h]
#pragma unroll
      for (int sel=0;sel<2;sel++){
        const int key = (kb*2+sel)*16 + l16;
        const s16x8 kf0 = *(const s16x8*)(KtC + key*72 + quad*8);
        const s16x8 kf1 = *(const s16x8*)(KtC + key*72 + 32 + quad*8);
#pragma unroll
        for (int g=0;g<2;g++){
          f32x4 z = f32x4{0.f,0.f,0.f,0.f};
          z = MFMA16(kf0, qf[g][0], z);
          z = MFMA16(kf1, qf[g][1], z);
          const float p0 = __builtin_amdgcn_exp2f(z[0]);
          const float p1 = __builtin_amdgcn_exp2f(z[1]);
          const float p2 = __builtin_amdgcn_exp2f(z[2]);
          const float p3 = __builtin_amdgcn_exp2f(z[3]);
          lr[g] += (trunc_bf(p0)+trunc_bf(p1)) + (trunc_bf(p2)+trunc_bf(p3));
          const u32 w0 = __builtin_amdgcn_perm(fbits(p1), fbits(p0), 0x07060302u);
          const u32 w1 = __builtin_amdgcn_perm(fbits(p3), fbits(p2), 0x07060302u);
          if (sel==0){ ew[g][0]=w0; ew[g][1]=w1; } else { ow[g][0]=w0; ow[g][1]=w1; }
        }
      }
      // in-register P redistribution via builtins (hazard-safe)
      s16x8 pf[2];
#pragma unroll
      for (int g=0;g<2;g++){
        const u32x2 r32 = __builtin_amdgcn_permlane32_swap(ew[g][0], ow[g][0], false, false);
        const u32x2 r16 = __builtin_amdgcn_permlane16_swap(r32[0], r32[1], false, false);
        const u32x2 s32 = __builtin_amdgcn_permlane32_swap(ew[g][1], ow[g][1], false, false);
        const u32x2 s16v = __builtin_amdgcn_permlane16_swap(s32[0], s32[1], false, false);
        u32x4 pw; pw[0]=r16[0]; pw[1]=s16v[0]; pw[2]=r16[1]; pw[3]=s16v[1];
        pf[g] = __builtin_bit_cast(s16x8, pw);
      }
      // OT += V^T·P^T for this kb
      __builtin_amdgcn_s_setprio(1);
#pragma unroll
      for (int td=0;td<4;td++){
        const s16x8 vf = *(const s16x8*)(VtC + (td*16+l16)*136 + kb*32 + quad*8);
#pragma unroll
        for (int g=0;g<2;g++)
          OT[g][td] = MFMA16(vf, pf[g], OT[g][td]);
      }
      __builtin_amdgcn_s_setprio(0);
    }
    __syncthreads();   // readers of buf[cur] done AND writes to buf[cur^1] visible
  }

  // epilogue: combine quad partials of l once, then scale + RNE pack
#pragma unroll
  for (int g=0;g<2;g++){
    float t = lr[g];
    t += __shfl_xor(t,16);
    t += __shfl_xor(t,32);
    const float linv = 1.0f / t;
    const int q = q0 + qw + g*16 + l16;
#pragma unroll
    for (int td=0;td<4;td++){
      u16x4 pk;
#pragma unroll
      for (int rg=0;rg<4;rg++) pk[rg] = f2b(OT[g][td][rg]*linv);
      *(u16x4*)(Out + (size_t)(nb*2048+q)*1024 + h*64 + td*16 + quad*4) = pk;
    }
  }
}

extern "C" void kernel_launch(void* const* d_in, const int* in_sizes, int n_in,
                              void* d_out, int out_size, void* d_ws, size_t ws_size,
                              hipStream_t stream)
{
  const float* x  = (const float*)d_in[0];
  const float* Wq = (const float*)d_in[1];  const float* bq = (const float*)d_in[2];
  const float* Aq = (const float*)d_in[3];  const float* Bq = (const float*)d_in[4];
  const float* Wk = (const float*)d_in[5];  const float* bk = (const float*)d_in[6];
  const float* Ak = (const float*)d_in[7];  const float* Bk = (const float*)d_in[8];
  const float* Wv = (const float*)d_in[9];  const float* bv = (const float*)d_in[10];
  const float* Av = (const float*)d_in[11]; const float* Bv = (const float*)d_in[12];
  const float* Wo = (const float*)d_in[13]; const float* bo = (const float*)d_in[14];
  const float* Ao = (const float*)d_in[15]; const float* Bo = (const float*)d_in[16];

  char* ws = (char*)d_ws;
  float* tq = (float*)(ws + 0);
  float* tk = (float*)(ws + 131072);
  float* tv = (float*)(ws + 262144);
  float* to = (float*)(ws + 393216);
  u16* xb  = (u16*)(ws + 524288);              // 8 MB; Ab aliases (xb dead after QKV)
  u16* Ab  = xb;
  u16* Wb  = (u16*)(ws + 524288 + 8388608);
  u16* Qb  = (u16*)(ws + 524288 + 2*8388608);
  u16* Kb  = (u16*)(ws + 524288 + 3*8388608);
  u16* Vtb = (u16*)(ws + 524288 + 4*8388608);

  lora_conv_kernel<true,3><<<dim3(2048),256,0,stream>>>(
      x, Aq, Ak, Av, tq, tk, tv, xb, Wq, Wk, Wv, Wo, Wb);
  gemm_qkv_kernel<<<dim3(24,32),256,0,stream>>>(xb, Wb, bq, bk, bv, tq, tk, tv,
                                                Bq, Bk, Bv, Qb, Kb, Vtb);
  attn_kernel<<<dim3(16,16,2),256,0,stream>>>(Qb, Kb, Vtb, Ab);
  lora_conv_kernel<false,1><<<dim3(1024),256,0,stream>>>(
      Ab, Ao, Ao, Ao, to, to, to, nullptr,
      nullptr, nullptr, nullptr, nullptr, nullptr);
  gemm_o_kernel<<<dim3(16,32),256,0,stream>>>(Ab, Wb + (size_t)3*1048576, bo, to, Bo,
                                              (float*)d_out);
}

// Round 4
// 240.512 us; speedup vs baseline: 1.1796x; 1.0091x over previous
//
#include <hip/hip_runtime.h>
#include <stdint.h>

typedef uint16_t u16;
typedef short s16x8 __attribute__((ext_vector_type(8)));
typedef float f32x4 __attribute__((ext_vector_type(4)));
typedef unsigned short u16x4 __attribute__((ext_vector_type(4)));
typedef uint32_t u32;
typedef u32 u32x2 __attribute__((ext_vector_type(2)));
typedef u32 u32x4 __attribute__((ext_vector_type(4)));

#define MFMA16(a,b,c) __builtin_amdgcn_mfma_f32_16x16x32_bf16((a),(b),(c),0,0,0)
#define QSCALE 0.18033688011112042f   // 0.125 * log2(e)

__device__ __forceinline__ float b2f(u16 b){
  union { u32 u; float f; } v; v.u = ((u32)b)<<16; return v.f;
}
__device__ __forceinline__ u16 f2b(float f){
  union { float f; u32 u; } v; v.f = f;
  return (u16)((v.u + 0x7fffu + ((v.u>>16)&1u))>>16);
}
__device__ __forceinline__ u32 fbits(float f){
  union { float f; u32 u; } v; v.f = f; return v.u;
}
__device__ __forceinline__ float trunc_bf(float f){
  union { u32 u; float f; } v; v.u = fbits(f) & 0xffff0000u; return v.f;
}
__device__ __forceinline__ void load_lds_16B(const void* g, void* l){
  __builtin_amdgcn_global_load_lds((const __attribute__((address_space(1))) void*)g,
                                   (__attribute__((address_space(3))) void*)l, 16, 0, 0);
}

// ---------------- merged LoRA t = X @ A^T  (+ optional W fp32->bf16 convert) -
// XF32 call: grid 2048. blocks [0,1024): lora rows (also emits xb);
//            blocks [1024,2048): convert W0..W3 -> Wb (independent, overlapped).
// !XF32 call: grid 1024, lora only.
template<bool XF32, int NMAT>
__global__ __launch_bounds__(256) void lora_conv_kernel(
    const void* __restrict__ Xv,
    const float* __restrict__ A0, const float* __restrict__ A1, const float* __restrict__ A2,
    float* __restrict__ T0, float* __restrict__ T1, float* __restrict__ T2,
    u16* __restrict__ xb,
    const float* __restrict__ W0, const float* __restrict__ W1,
    const float* __restrict__ W2, const float* __restrict__ W3,
    u16* __restrict__ Wb)
{
  if (XF32 && blockIdx.x >= 1024){
    const int cv = blockIdx.x - 1024;
    const int y = cv>>8;
    const float* src = (y==0)?W0:(y==1)?W1:(y==2)?W2:W3;
    u16* dst = Wb + (size_t)y*1048576;
    const int g = (cv&255)*256 + threadIdx.x;
#pragma unroll
    for (int t=0;t<4;t++){
      const int i4 = g + t*65536;
      const f32x4 v = *(const f32x4*)(src + (size_t)i4*4);
      u16x4 o;
#pragma unroll
      for (int j=0;j<4;j++) o[j] = f2b(v[j]);
      *(u16x4*)(dst + (size_t)i4*4) = o;
    }
    return;
  }

  const int wid = threadIdx.x>>6, lane = threadIdx.x&63;
  const int m = blockIdx.x*4 + wid;

  float xf[16];
  if (XF32){
    const float* xp = (const float*)Xv + (size_t)m*1024 + lane*16;
#pragma unroll
    for (int q=0;q<4;q++){
      const f32x4 v = *(const f32x4*)(xp + q*4);
#pragma unroll
      for (int j=0;j<4;j++) xf[q*4+j] = v[j];
    }
    u16* xbp = xb + (size_t)m*1024 + lane*16;
#pragma unroll
    for (int q=0;q<4;q++){
      u16x4 o;
#pragma unroll
      for (int j=0;j<4;j++) o[j] = f2b(xf[q*4+j]);
      *(u16x4*)(xbp + q*4) = o;
    }
  } else {
    const u16* xp = (const u16*)Xv + (size_t)m*1024 + lane*16;
#pragma unroll
    for (int j=0;j<16;j++) xf[j] = b2f(xp[j]);
  }

#pragma unroll
  for (int mat=0; mat<NMAT; mat++){
    const float* A = (mat==0)?A0:(mat==1)?A1:A2;
    float* T = (mat==0)?T0:(mat==1)?T1:T2;
    float accv[8];
#pragma unroll
    for (int r=0;r<8;r++){
      const float* ap = A + r*1024 + lane*16;
      float s = 0.f;
#pragma unroll
      for (int q=0;q<4;q++){
        const f32x4 av = *(const f32x4*)(ap + q*4);
#pragma unroll
        for (int j=0;j<4;j++) s += xf[q*4+j]*av[j];
      }
      accv[r] = s;
    }
#pragma unroll
    for (int r=0;r<8;r++){
      float s = accv[r];
      s += __shfl_xor(s,1);  s += __shfl_xor(s,2);  s += __shfl_xor(s,4);
      s += __shfl_xor(s,8);  s += __shfl_xor(s,16); s += __shfl_xor(s,32);
      accv[r] = s;
    }
    if (lane==0){
#pragma unroll
      for (int r=0;r<8;r++) T[(size_t)m*8 + r] = accv[r];
    }
  }
}

// ---------------- fused QKV GEMM (m97-style; LoRA epilogue via K=8 MFMA) -----
// grid (24,32): proj = bx>>3 (0=Q,1=K,2=V), n0=(bx&7)*128, m0=by*128.
__global__ __launch_bounds__(256,2) void gemm_qkv_kernel(
    const u16* __restrict__ Xb, const u16* __restrict__ Wb,
    const float* __restrict__ bq, const float* __restrict__ bk, const float* __restrict__ bv,
    const float* __restrict__ tq, const float* __restrict__ tk, const float* __restrict__ tv,
    const float* __restrict__ Blq, const float* __restrict__ Blk, const float* __restrict__ Blv,
    u16* __restrict__ Qb, u16* __restrict__ Kb, u16* __restrict__ Vtb)
{
  __shared__ u16 At[128*32];
  __shared__ u16 Bt[128*32];
  const int tid = threadIdx.x;
  const int wid = tid>>6, lane = tid&63;
  const int quad = lane>>4, l16 = lane&15;
  const int wm = wid>>1, wn = wid&1;
  const int proj = blockIdx.x>>3;
  const int n0 = (blockIdx.x&7)<<7, m0 = blockIdx.y<<7;
  const u16* W = Wb + (size_t)proj*1048576;
  const float* bias = (proj==0)?bq:(proj==1)?bk:bv;
  const float* T    = (proj==0)?tq:(proj==1)?tk:tv;
  const float* Bl   = (proj==0)?Blq:(proj==1)?Blk:Blv;
  const float scale = (proj==0)?QSCALE:1.0f;

  f32x4 acc[4][4];
#pragma unroll
  for (int i=0;i<4;i++)
#pragma unroll
    for (int j=0;j<4;j++) acc[i][j] = f32x4{0.f,0.f,0.f,0.f};

  for (int k0=0;k0<1024;k0+=32){
#pragma unroll
    for (int p=0;p<2;p++){
      const int s = wid*128 + p*64 + lane;
      const int row = s>>2, c = s&3;
      load_lds_16B(Xb + (size_t)(m0+row)*1024 + k0 + c*8, At + (wid*128+p*64)*8);
      load_lds_16B(W  + (size_t)(n0+row)*1024 + k0 + c*8, Bt + (wid*128+p*64)*8);
    }
    __syncthreads();
    s16x8 af[4], bfr[4];
#pragma unroll
    for (int t=0;t<4;t++){
      const int r = wm*64 + t*16 + l16;
      af[t]  = *(const s16x8*)(At + r*32 + quad*8);
      const int c = wn*64 + t*16 + l16;
      bfr[t] = *(const s16x8*)(Bt + c*32 + quad*8);
    }
#pragma unroll
    for (int tm=0;tm<4;tm++)
#pragma unroll
      for (int tn=0;tn<4;tn++)
        acc[tm][tn] = MFMA16(af[tm], bfr[tn], acc[tm][tn]);
    __syncthreads();
  }

  // LoRA term via one K=8 (zero-padded to 32) MFMA per acc tile: quad0 holds k=0..7
  s16x8 tf[4], bfl[4];
#pragma unroll
  for (int t=0;t<4;t++){ tf[t] = s16x8{0,0,0,0,0,0,0,0}; bfl[t] = s16x8{0,0,0,0,0,0,0,0}; }
  if (quad==0){
#pragma unroll
    for (int tm=0;tm<4;tm++){
      const float* tp = T + (size_t)(m0 + wm*64 + tm*16 + l16)*8;
      const f32x4 a0 = *(const f32x4*)(tp);
      const f32x4 a1 = *(const f32x4*)(tp+4);
#pragma unroll
      for (int j=0;j<4;j++){ tf[tm][j] = (short)f2b(2.0f*a0[j]); tf[tm][4+j] = (short)f2b(2.0f*a1[j]); }
    }
#pragma unroll
    for (int tn=0;tn<4;tn++){
      const float* bp = Bl + (size_t)(n0 + wn*64 + tn*16 + l16)*8;
      const f32x4 b0 = *(const f32x4*)(bp);
      const f32x4 b1 = *(const f32x4*)(bp+4);
#pragma unroll
      for (int j=0;j<4;j++){ bfl[tn][j] = (short)f2b(b0[j]); bfl[tn][4+j] = (short)f2b(b1[j]); }
    }
  }
#pragma unroll
  for (int tm=0;tm<4;tm++)
#pragma unroll
    for (int tn=0;tn<4;tn++)
      acc[tm][tn] = MFMA16(tf[tm], bfl[tn], acc[tm][tn]);

#pragma unroll
  for (int tn=0;tn<4;tn++){
    const int n = n0 + wn*64 + tn*16 + l16;
    const float bn = bias[n];
#pragma unroll
    for (int tm=0;tm<4;tm++){
      const int mb = m0 + wm*64 + tm*16 + quad*4;
      if (proj==0){
#pragma unroll
        for (int rg=0;rg<4;rg++) Qb[(size_t)(mb+rg)*1024 + n] = f2b((acc[tm][tn][rg]+bn)*scale);
      } else if (proj==1){
#pragma unroll
        for (int rg=0;rg<4;rg++) Kb[(size_t)(mb+rg)*1024 + n] = f2b(acc[tm][tn][rg]+bn);
      } else {
        const int batch = mb>>11, sI = mb&2047;
        const int hh = n>>6, dd = n&63;
        u16x4 pk;
#pragma unroll
        for (int rg=0;rg<4;rg++) pk[rg] = f2b(acc[tm][tn][rg]+bn);
        *(u16x4*)(Vtb + (size_t)((batch*16+hh)*64+dd)*2048 + sI) = pk;
      }
    }
  }
}

// ---------------- O-proj GEMM: 128x64 tiles, fp32 out, MFMA LoRA epilogue ----
__global__ __launch_bounds__(256,2) void gemm_o_kernel(
    const u16* __restrict__ Xb, const u16* __restrict__ W,
    const float* __restrict__ bias, const float* __restrict__ T,
    const float* __restrict__ Bl, float* __restrict__ Out)
{
  __shared__ u16 At[128*32];
  __shared__ u16 Bt[64*32];
  const int tid = threadIdx.x;
  const int wid = tid>>6, lane = tid&63;
  const int quad = lane>>4, l16 = lane&15;
  const int wm = wid>>1, wn = wid&1;
  const int m0 = blockIdx.y<<7, n0 = blockIdx.x<<6;

  f32x4 acc[4][2];
#pragma unroll
  for (int i=0;i<4;i++)
#pragma unroll
    for (int j=0;j<2;j++) acc[i][j] = f32x4{0.f,0.f,0.f,0.f};

  for (int k0=0;k0<1024;k0+=32){
#pragma unroll
    for (int p=0;p<2;p++){
      const int s = wid*128 + p*64 + lane;
      const int row = s>>2, c = s&3;
      load_lds_16B(Xb + (size_t)(m0+row)*1024 + k0 + c*8, At + (wid*128+p*64)*8);
    }
    { const int s = wid*64 + lane;
      const int row = s>>2, c = s&3;
      load_lds_16B(W + (size_t)(n0+row)*1024 + k0 + c*8, Bt + (wid*64)*8); }
    __syncthreads();
    s16x8 af[4], bfr[2];
#pragma unroll
    for (int t=0;t<4;t++){
      const int r = wm*64 + t*16 + l16;
      af[t] = *(const s16x8*)(At + r*32 + quad*8);
    }
#pragma unroll
    for (int t=0;t<2;t++){
      const int c = wn*32 + t*16 + l16;
      bfr[t] = *(const s16x8*)(Bt + c*32 + quad*8);
    }
#pragma unroll
    for (int tm=0;tm<4;tm++)
#pragma unroll
      for (int tn=0;tn<2;tn++)
        acc[tm][tn] = MFMA16(af[tm], bfr[tn], acc[tm][tn]);
    __syncthreads();
  }

  s16x8 tf[4], bfl[2];
#pragma unroll
  for (int t=0;t<4;t++) tf[t] = s16x8{0,0,0,0,0,0,0,0};
#pragma unroll
  for (int t=0;t<2;t++) bfl[t] = s16x8{0,0,0,0,0,0,0,0};
  if (quad==0){
#pragma unroll
    for (int tm=0;tm<4;tm++){
      const float* tp = T + (size_t)(m0 + wm*64 + tm*16 + l16)*8;
      const f32x4 a0 = *(const f32x4*)(tp);
      const f32x4 a1 = *(const f32x4*)(tp+4);
#pragma unroll
      for (int j=0;j<4;j++){ tf[tm][j] = (short)f2b(2.0f*a0[j]); tf[tm][4+j] = (short)f2b(2.0f*a1[j]); }
    }
#pragma unroll
    for (int tn=0;tn<2;tn++){
      const float* bp = Bl + (size_t)(n0 + wn*32 + tn*16 + l16)*8;
      const f32x4 b0 = *(const f32x4*)(bp);
      const f32x4 b1 = *(const f32x4*)(bp+4);
#pragma unroll
      for (int j=0;j<4;j++){ bfl[tn][j] = (short)f2b(b0[j]); bfl[tn][4+j] = (short)f2b(b1[j]); }
    }
  }
#pragma unroll
  for (int tm=0;tm<4;tm++)
#pragma unroll
    for (int tn=0;tn<2;tn++)
      acc[tm][tn] = MFMA16(tf[tm], bfl[tn], acc[tm][tn]);

#pragma unroll
  for (int tn=0;tn<2;tn++){
    const int n = n0 + wn*32 + tn*16 + l16;
    const float bn = bias[n];
#pragma unroll
    for (int tm=0;tm<4;tm++){
      const int mb = m0 + wm*64 + tm*16 + quad*4;
#pragma unroll
      for (int rg=0;rg<4;rg++)
        Out[(size_t)(mb+rg)*1024 + n] = acc[tm][tn][rg] + bn;
    }
  }
}

// ---------------- MFMA flash attention v4 ------------------------------------
// grid (16,16,2), block 512 (8 waves, 16 q-cols/wave). Same verified data path
// as v3b (permlane-swap P redistribution, direct exp2, truncated-P l-sum,
// double-buffered K/V, one barrier/tile) but DOUBLE the occupancy:
// 2 blocks/CU x 8 waves = 16 waves/CU = 4 waves/SIMD (was 2). R3 showed the
// kernel is latency-bound (Occ 17%, MfmaUtil 25 + VALU 43, pipes idle >50%);
// more resident waves fill the QK->exp2->swap->PV dependency stalls.
// LDS: 2*(128*72 + 64*136)*2B = 71680 B -> 2 blocks/CU (143 KB).
__global__ __launch_bounds__(512,4) void attn_kernel(
    const u16* __restrict__ Q, const u16* __restrict__ K,
    const u16* __restrict__ Vt, u16* __restrict__ Out)
{
  __shared__ u16 KtB[2][128*72];
  __shared__ u16 VtB[2][64*136];
  const int tid = threadIdx.x;
  const int wid = tid>>6, lane = tid&63;
  const int quad = lane>>4, l16 = lane&15;
  const int q0 = blockIdx.x<<7;
  const int h = blockIdx.y, nb = blockIdx.z;
  const int qw = wid*16;                    // wave's 16 q-cols: qw + l16

  s16x8 qf[2];
  {
    const int row = q0 + qw + l16;
#pragma unroll
    for (int dh=0;dh<2;dh++)
      qf[dh] = *(const s16x8*)(Q + (size_t)(nb*2048+row)*1024 + h*64 + dh*32 + quad*8);
  }
  f32x4 OT[4];                              // C: d = td*16+quad*4+rg, q-col = l16
  float lr = 0.f;
#pragma unroll
  for (int td=0;td<4;td++) OT[td] = f32x4{0.f,0.f,0.f,0.f};

  s16x8 kreg[2], vreg[2];
  auto LOADT = [&](int kn){
#pragma unroll
    for (int p=0;p<2;p++){
      const int s = p*512 + tid;
      kreg[p] = *(const s16x8*)(K + (size_t)(nb*2048+kn+(s>>3))*1024 + h*64 + (s&7)*8);
      vreg[p] = *(const s16x8*)(Vt + (size_t)((nb*16+h)*64+(s>>4))*2048 + kn + (s&15)*8);
    }
  };
  auto WRITET = [&](int b){
    u16* Ktb = KtB[b]; u16* Vtb = VtB[b];
#pragma unroll
    for (int p=0;p<2;p++){
      const int s = p*512 + tid;
      *(s16x8*)(Ktb + (s>>3)*72 + (s&7)*8) = kreg[p];
      *(s16x8*)(Vtb + (s>>4)*136 + (s&15)*8) = vreg[p];
    }
  };

  LOADT(0);
  WRITET(0);
  LOADT(128);
  __syncthreads();

  for (int t=0;t<16;t++){
    const int cur = t&1;
    if (t < 15) WRITET(cur^1);              // regs hold tile t+1; buf consumed at t-1
    if (t < 14) LOADT((t+2)*128);           // latency hides under this tile's math
    const u16* KtC = KtB[cur];
    const u16* VtC = VtB[cur];

#pragma unroll
    for (int kb=0;kb<4;kb++){
      u32 ew[2], ow[2];                     // packed bf16 P words [h]
#pragma unroll
      for (int sel=0;sel<2;sel++){
        const int key = (kb*2+sel)*16 + l16;
        const s16x8 kf0 = *(const s16x8*)(KtC + key*72 + quad*8);
        const s16x8 kf1 = *(const s16x8*)(KtC + key*72 + 32 + quad*8);
        f32x4 z = f32x4{0.f,0.f,0.f,0.f};
        z = MFMA16(kf0, qf[0], z);
        z = MFMA16(kf1, qf[1], z);
        const float p0 = __builtin_amdgcn_exp2f(z[0]);
        const float p1 = __builtin_amdgcn_exp2f(z[1]);
        const float p2 = __builtin_amdgcn_exp2f(z[2]);
        const float p3 = __builtin_amdgcn_exp2f(z[3]);
        lr += (trunc_bf(p0)+trunc_bf(p1)) + (trunc_bf(p2)+trunc_bf(p3));
        const u32 w0 = __builtin_amdgcn_perm(fbits(p1), fbits(p0), 0x07060302u);
        const u32 w1 = __builtin_amdgcn_perm(fbits(p3), fbits(p2), 0x07060302u);
        if (sel==0){ ew[0]=w0; ew[1]=w1; } else { ow[0]=w0; ow[1]=w1; }
      }
      // in-register P redistribution via builtins (hazard-safe)
      s16x8 pf;
      {
        const u32x2 r32 = __builtin_amdgcn_permlane32_swap(ew[0], ow[0], false, false);
        const u32x2 r16 = __builtin_amdgcn_permlane16_swap(r32[0], r32[1], false, false);
        const u32x2 s32 = __builtin_amdgcn_permlane32_swap(ew[1], ow[1], false, false);
        const u32x2 s16v = __builtin_amdgcn_permlane16_swap(s32[0], s32[1], false, false);
        u32x4 pw; pw[0]=r16[0]; pw[1]=s16v[0]; pw[2]=r16[1]; pw[3]=s16v[1];
        pf = __builtin_bit_cast(s16x8, pw);
      }
      // OT += V^T·P^T for this kb
      __builtin_amdgcn_s_setprio(1);
#pragma unroll
      for (int td=0;td<4;td++){
        const s16x8 vf = *(const s16x8*)(VtC + (td*16+l16)*136 + kb*32 + quad*8);
        OT[td] = MFMA16(vf, pf, OT[td]);
      }
      __builtin_amdgcn_s_setprio(0);
    }
    __syncthreads();   // readers of buf[cur] done AND writes to buf[cur^1] visible
  }

  // epilogue: combine quad partials of l once, then scale + RNE pack
  {
    float t = lr;
    t += __shfl_xor(t,16);
    t += __shfl_xor(t,32);
    const float linv = 1.0f / t;
    const int q = q0 + qw + l16;
#pragma unroll
    for (int td=0;td<4;td++){
      u16x4 pk;
#pragma unroll
      for (int rg=0;rg<4;rg++) pk[rg] = f2b(OT[td][rg]*linv);
      *(u16x4*)(Out + (size_t)(nb*2048+q)*1024 + h*64 + td*16 + quad*4) = pk;
    }
  }
}

extern "C" void kernel_launch(void* const* d_in, const int* in_sizes, int n_in,
                              void* d_out, int out_size, void* d_ws, size_t ws_size,
                              hipStream_t stream)
{
  const float* x  = (const float*)d_in[0];
  const float* Wq = (const float*)d_in[1];  const float* bq = (const float*)d_in[2];
  const float* Aq = (const float*)d_in[3];  const float* Bq = (const float*)d_in[4];
  const float* Wk = (const float*)d_in[5];  const float* bk = (const float*)d_in[6];
  const float* Ak = (const float*)d_in[7];  const float* Bk = (const float*)d_in[8];
  const float* Wv = (const float*)d_in[9];  const float* bv = (const float*)d_in[10];
  const float* Av = (const float*)d_in[11]; const float* Bv = (const float*)d_in[12];
  const float* Wo = (const float*)d_in[13]; const float* bo = (const float*)d_in[14];
  const float* Ao = (const float*)d_in[15]; const float* Bo = (const float*)d_in[16];

  char* ws = (char*)d_ws;
  float* tq = (float*)(ws + 0);
  float* tk = (float*)(ws + 131072);
  float* tv = (float*)(ws + 262144);
  float* to = (float*)(ws + 393216);
  u16* xb  = (u16*)(ws + 524288);              // 8 MB; Ab aliases (xb dead after QKV)
  u16* Ab  = xb;
  u16* Wb  = (u16*)(ws + 524288 + 8388608);
  u16* Qb  = (u16*)(ws + 524288 + 2*8388608);
  u16* Kb  = (u16*)(ws + 524288 + 3*8388608);
  u16* Vtb = (u16*)(ws + 524288 + 4*8388608);

  lora_conv_kernel<true,3><<<dim3(2048),256,0,stream>>>(
      x, Aq, Ak, Av, tq, tk, tv, xb, Wq, Wk, Wv, Wo, Wb);
  gemm_qkv_kernel<<<dim3(24,32),256,0,stream>>>(xb, Wb, bq, bk, bv, tq, tk, tv,
                                                Bq, Bk, Bv, Qb, Kb, Vtb);
  attn_kernel<<<dim3(16,16,2),512,0,stream>>>(Qb, Kb, Vtb, Ab);
  lora_conv_kernel<false,1><<<dim3(1024),256,0,stream>>>(
      Ab, Ao, Ao, Ao, to, to, to, nullptr,
      nullptr, nullptr, nullptr, nullptr, nullptr);
  gemm_o_kernel<<<dim3(16,32),256,0,stream>>>(Ab, Wb + (size_t)3*1048576, bo, to, Bo,
                                              (float*)d_out);
}

// Round 5
// 238.599 us; speedup vs baseline: 1.1890x; 1.0080x over previous
//
#include <hip/hip_runtime.h>
#include <stdint.h>

typedef uint16_t u16;
typedef short s16x8 __attribute__((ext_vector_type(8)));
typedef float f32x4 __attribute__((ext_vector_type(4)));
typedef unsigned short u16x4 __attribute__((ext_vector_type(4)));
typedef uint32_t u32;
typedef u32 u32x2 __attribute__((ext_vector_type(2)));
typedef u32 u32x4 __attribute__((ext_vector_type(4)));

#define MFMA16(a,b,c) __builtin_amdgcn_mfma_f32_16x16x32_bf16((a),(b),(c),0,0,0)
#define QSCALE 0.18033688011112042f   // 0.125 * log2(e)

__device__ __forceinline__ float b2f(u16 b){
  union { u32 u; float f; } v; v.u = ((u32)b)<<16; return v.f;
}
__device__ __forceinline__ u16 f2b(float f){
  union { float f; u32 u; } v; v.f = f;
  return (u16)((v.u + 0x7fffu + ((v.u>>16)&1u))>>16);
}
__device__ __forceinline__ u32 fbits(float f){
  union { float f; u32 u; } v; v.f = f; return v.u;
}
__device__ __forceinline__ void load_lds_16B(const void* g, void* l){
  __builtin_amdgcn_global_load_lds((const __attribute__((address_space(1))) void*)g,
                                   (__attribute__((address_space(3))) void*)l, 16, 0, 0);
}

// ---------------- merged LoRA t = X @ A^T  (+ optional W fp32->bf16 convert) -
template<bool XF32, int NMAT>
__global__ __launch_bounds__(256) void lora_conv_kernel(
    const void* __restrict__ Xv,
    const float* __restrict__ A0, const float* __restrict__ A1, const float* __restrict__ A2,
    float* __restrict__ T0, float* __restrict__ T1, float* __restrict__ T2,
    u16* __restrict__ xb,
    const float* __restrict__ W0, const float* __restrict__ W1,
    const float* __restrict__ W2, const float* __restrict__ W3,
    u16* __restrict__ Wb)
{
  if (XF32 && blockIdx.x >= 1024){
    const int cv = blockIdx.x - 1024;
    const int y = cv>>8;
    const float* src = (y==0)?W0:(y==1)?W1:(y==2)?W2:W3;
    u16* dst = Wb + (size_t)y*1048576;
    const int g = (cv&255)*256 + threadIdx.x;
#pragma unroll
    for (int t=0;t<4;t++){
      const int i4 = g + t*65536;
      const f32x4 v = *(const f32x4*)(src + (size_t)i4*4);
      u16x4 o;
#pragma unroll
      for (int j=0;j<4;j++) o[j] = f2b(v[j]);
      *(u16x4*)(dst + (size_t)i4*4) = o;
    }
    return;
  }

  const int wid = threadIdx.x>>6, lane = threadIdx.x&63;
  const int m = blockIdx.x*4 + wid;

  float xf[16];
  if (XF32){
    const float* xp = (const float*)Xv + (size_t)m*1024 + lane*16;
#pragma unroll
    for (int q=0;q<4;q++){
      const f32x4 v = *(const f32x4*)(xp + q*4);
#pragma unroll
      for (int j=0;j<4;j++) xf[q*4+j] = v[j];
    }
    u16* xbp = xb + (size_t)m*1024 + lane*16;
#pragma unroll
    for (int q=0;q<4;q++){
      u16x4 o;
#pragma unroll
      for (int j=0;j<4;j++) o[j] = f2b(xf[q*4+j]);
      *(u16x4*)(xbp + q*4) = o;
    }
  } else {
    const u16* xp = (const u16*)Xv + (size_t)m*1024 + lane*16;
#pragma unroll
    for (int j=0;j<16;j++) xf[j] = b2f(xp[j]);
  }

#pragma unroll
  for (int mat=0; mat<NMAT; mat++){
    const float* A = (mat==0)?A0:(mat==1)?A1:A2;
    float* T = (mat==0)?T0:(mat==1)?T1:T2;
    float accv[8];
#pragma unroll
    for (int r=0;r<8;r++){
      const float* ap = A + r*1024 + lane*16;
      float s = 0.f;
#pragma unroll
      for (int q=0;q<4;q++){
        const f32x4 av = *(const f32x4*)(ap + q*4);
#pragma unroll
        for (int j=0;j<4;j++) s += xf[q*4+j]*av[j];
      }
      accv[r] = s;
    }
#pragma unroll
    for (int r=0;r<8;r++){
      float s = accv[r];
      s += __shfl_xor(s,1);  s += __shfl_xor(s,2);  s += __shfl_xor(s,4);
      s += __shfl_xor(s,8);  s += __shfl_xor(s,16); s += __shfl_xor(s,32);
      accv[r] = s;
    }
    if (lane==0){
#pragma unroll
      for (int r=0;r<8;r++) T[(size_t)m*8 + r] = accv[r];
    }
  }
}

// ---------------- fused QKV GEMM (m97-style; LoRA epilogue via K=8 MFMA) -----
__global__ __launch_bounds__(256,2) void gemm_qkv_kernel(
    const u16* __restrict__ Xb, const u16* __restrict__ Wb,
    const float* __restrict__ bq, const float* __restrict__ bk, const float* __restrict__ bv,
    const float* __restrict__ tq, const float* __restrict__ tk, const float* __restrict__ tv,
    const float* __restrict__ Blq, const float* __restrict__ Blk, const float* __restrict__ Blv,
    u16* __restrict__ Qb, u16* __restrict__ Kb, u16* __restrict__ Vtb)
{
  __shared__ u16 At[128*32];
  __shared__ u16 Bt[128*32];
  const int tid = threadIdx.x;
  const int wid = tid>>6, lane = tid&63;
  const int quad = lane>>4, l16 = lane&15;
  const int wm = wid>>1, wn = wid&1;
  const int proj = blockIdx.x>>3;
  const int n0 = (blockIdx.x&7)<<7, m0 = blockIdx.y<<7;
  const u16* W = Wb + (size_t)proj*1048576;
  const float* bias = (proj==0)?bq:(proj==1)?bk:bv;
  const float* T    = (proj==0)?tq:(proj==1)?tk:tv;
  const float* Bl   = (proj==0)?Blq:(proj==1)?Blk:Blv;
  const float scale = (proj==0)?QSCALE:1.0f;

  f32x4 acc[4][4];
#pragma unroll
  for (int i=0;i<4;i++)
#pragma unroll
    for (int j=0;j<4;j++) acc[i][j] = f32x4{0.f,0.f,0.f,0.f};

  for (int k0=0;k0<1024;k0+=32){
#pragma unroll
    for (int p=0;p<2;p++){
      const int s = wid*128 + p*64 + lane;
      const int row = s>>2, c = s&3;
      load_lds_16B(Xb + (size_t)(m0+row)*1024 + k0 + c*8, At + (wid*128+p*64)*8);
      load_lds_16B(W  + (size_t)(n0+row)*1024 + k0 + c*8, Bt + (wid*128+p*64)*8);
    }
    __syncthreads();
    s16x8 af[4], bfr[4];
#pragma unroll
    for (int t=0;t<4;t++){
      const int r = wm*64 + t*16 + l16;
      af[t]  = *(const s16x8*)(At + r*32 + quad*8);
      const int c = wn*64 + t*16 + l16;
      bfr[t] = *(const s16x8*)(Bt + c*32 + quad*8);
    }
#pragma unroll
    for (int tm=0;tm<4;tm++)
#pragma unroll
      for (int tn=0;tn<4;tn++)
        acc[tm][tn] = MFMA16(af[tm], bfr[tn], acc[tm][tn]);
    __syncthreads();
  }

  // LoRA term via one K=8 (zero-padded to 32) MFMA per acc tile: quad0 holds k=0..7
  s16x8 tf[4], bfl[4];
#pragma unroll
  for (int t=0;t<4;t++){ tf[t] = s16x8{0,0,0,0,0,0,0,0}; bfl[t] = s16x8{0,0,0,0,0,0,0,0}; }
  if (quad==0){
#pragma unroll
    for (int tm=0;tm<4;tm++){
      const float* tp = T + (size_t)(m0 + wm*64 + tm*16 + l16)*8;
      const f32x4 a0 = *(const f32x4*)(tp);
      const f32x4 a1 = *(const f32x4*)(tp+4);
#pragma unroll
      for (int j=0;j<4;j++){ tf[tm][j] = (short)f2b(2.0f*a0[j]); tf[tm][4+j] = (short)f2b(2.0f*a1[j]); }
    }
#pragma unroll
    for (int tn=0;tn<4;tn++){
      const float* bp = Bl + (size_t)(n0 + wn*64 + tn*16 + l16)*8;
      const f32x4 b0 = *(const f32x4*)(bp);
      const f32x4 b1 = *(const f32x4*)(bp+4);
#pragma unroll
      for (int j=0;j<4;j++){ bfl[tn][j] = (short)f2b(b0[j]); bfl[tn][4+j] = (short)f2b(b1[j]); }
    }
  }
#pragma unroll
  for (int tm=0;tm<4;tm++)
#pragma unroll
    for (int tn=0;tn<4;tn++)
      acc[tm][tn] = MFMA16(tf[tm], bfl[tn], acc[tm][tn]);

#pragma unroll
  for (int tn=0;tn<4;tn++){
    const int n = n0 + wn*64 + tn*16 + l16;
    const float bn = bias[n];
#pragma unroll
    for (int tm=0;tm<4;tm++){
      const int mb = m0 + wm*64 + tm*16 + quad*4;
      if (proj==0){
#pragma unroll
        for (int rg=0;rg<4;rg++) Qb[(size_t)(mb+rg)*1024 + n] = f2b((acc[tm][tn][rg]+bn)*scale);
      } else if (proj==1){
#pragma unroll
        for (int rg=0;rg<4;rg++) Kb[(size_t)(mb+rg)*1024 + n] = f2b(acc[tm][tn][rg]+bn);
      } else {
        const int batch = mb>>11, sI = mb&2047;
        const int hh = n>>6, dd = n&63;
        u16x4 pk;
#pragma unroll
        for (int rg=0;rg<4;rg++) pk[rg] = f2b(acc[tm][tn][rg]+bn);
        *(u16x4*)(Vtb + (size_t)((batch*16+hh)*64+dd)*2048 + sI) = pk;
      }
    }
  }
}

// ---------------- O-proj GEMM: 128x64 tiles, fp32 out, MFMA LoRA epilogue ----
__global__ __launch_bounds__(256,2) void gemm_o_kernel(
    const u16* __restrict__ Xb, const u16* __restrict__ W,
    const float* __restrict__ bias, const float* __restrict__ T,
    const float* __restrict__ Bl, float* __restrict__ Out)
{
  __shared__ u16 At[128*32];
  __shared__ u16 Bt[64*32];
  const int tid = threadIdx.x;
  const int wid = tid>>6, lane = tid&63;
  const int quad = lane>>4, l16 = lane&15;
  const int wm = wid>>1, wn = wid&1;
  const int m0 = blockIdx.y<<7, n0 = blockIdx.x<<6;

  f32x4 acc[4][2];
#pragma unroll
  for (int i=0;i<4;i++)
#pragma unroll
    for (int j=0;j<2;j++) acc[i][j] = f32x4{0.f,0.f,0.f,0.f};

  for (int k0=0;k0<1024;k0+=32){
#pragma unroll
    for (int p=0;p<2;p++){
      const int s = wid*128 + p*64 + lane;
      const int row = s>>2, c = s&3;
      load_lds_16B(Xb + (size_t)(m0+row)*1024 + k0 + c*8, At + (wid*128+p*64)*8);
    }
    { const int s = wid*64 + lane;
      const int row = s>>2, c = s&3;
      load_lds_16B(W + (size_t)(n0+row)*1024 + k0 + c*8, Bt + (wid*64)*8); }
    __syncthreads();
    s16x8 af[4], bfr[2];
#pragma unroll
    for (int t=0;t<4;t++){
      const int r = wm*64 + t*16 + l16;
      af[t] = *(const s16x8*)(At + r*32 + quad*8);
    }
#pragma unroll
    for (int t=0;t<2;t++){
      const int c = wn*32 + t*16 + l16;
      bfr[t] = *(const s16x8*)(Bt + c*32 + quad*8);
    }
#pragma unroll
    for (int tm=0;tm<4;tm++)
#pragma unroll
      for (int tn=0;tn<2;tn++)
        acc[tm][tn] = MFMA16(af[tm], bfr[tn], acc[tm][tn]);
    __syncthreads();
  }

  s16x8 tf[4], bfl[2];
#pragma unroll
  for (int t=0;t<4;t++) tf[t] = s16x8{0,0,0,0,0,0,0,0};
#pragma unroll
  for (int t=0;t<2;t++) bfl[t] = s16x8{0,0,0,0,0,0,0,0};
  if (quad==0){
#pragma unroll
    for (int tm=0;tm<4;tm++){
      const float* tp = T + (size_t)(m0 + wm*64 + tm*16 + l16)*8;
      const f32x4 a0 = *(const f32x4*)(tp);
      const f32x4 a1 = *(const f32x4*)(tp+4);
#pragma unroll
      for (int j=0;j<4;j++){ tf[tm][j] = (short)f2b(2.0f*a0[j]); tf[tm][4+j] = (short)f2b(2.0f*a1[j]); }
    }
#pragma unroll
    for (int tn=0;tn<2;tn++){
      const float* bp = Bl + (size_t)(n0 + wn*32 + tn*16 + l16)*8;
      const f32x4 b0 = *(const f32x4*)(bp);
      const f32x4 b1 = *(const f32x4*)(bp+4);
#pragma unroll
      for (int j=0;j<4;j++){ bfl[tn][j] = (short)f2b(b0[j]); bfl[tn][4+j] = (short)f2b(b1[j]); }
    }
  }
#pragma unroll
  for (int tm=0;tm<4;tm++)
#pragma unroll
    for (int tn=0;tn<2;tn++)
      acc[tm][tn] = MFMA16(tf[tm], bfl[tn], acc[tm][tn]);

#pragma unroll
  for (int tn=0;tn<2;tn++){
    const int n = n0 + wn*32 + tn*16 + l16;
    const float bn = bias[n];
#pragma unroll
    for (int tm=0;tm<4;tm++){
      const int mb = m0 + wm*64 + tm*16 + quad*4;
#pragma unroll
      for (int rg=0;rg<4;rg++)
        Out[(size_t)(mb+rg)*1024 + n] = acc[tm][tn][rg] + bn;
    }
  }
}

// ---------------- MFMA flash attention v5 ------------------------------------
// grid (16,16,2), block 512. 8 waves = 4 q-groups (32 q, 2 MFMA q-tiles ->
// kf/vf 2-way reuse restored, v4's doubled LDS traffic undone) x 2 key-halves
// (64 keys each; partial O/l merged once via LDS at epilogue).
// l-sum on the MATRIX pipe: one extra MFMA per (kb,g) with all-ones A-frag
// computes sum_k P_bf16 (same truncated-bf16 P as PV -> numerics consistent),
// deleting the per-element trunc+add VALU chain and the epilogue shuffles.
// Double-buffered K/V, one barrier/tile, permlane-swap P redistribution.
// LDS: 2*(128*72 + 64*136)*2B = 71680 B -> 2 blocks/CU, 4 waves/SIMD.
__global__ __launch_bounds__(512,4) void attn_kernel(
    const u16* __restrict__ Q, const u16* __restrict__ K,
    const u16* __restrict__ Vt, u16* __restrict__ Out)
{
  __shared__ u16 KtB[2][128*72];
  __shared__ u16 VtB[2][64*136];
  const int tid = threadIdx.x;
  const int wid = tid>>6, lane = tid&63;
  const int quad = lane>>4, l16 = lane&15;
  const int q0 = blockIdx.x<<7;
  const int h = blockIdx.y, nb = blockIdx.z;
  const int qg = wid>>1;                    // q-group 0..3: 32 q-cols
  const int kh = wid&1;                     // key-half 0..1: 64 keys/tile
  const int qw = qg*32;                     // q-cols: qw + g*16 + l16

  s16x8 qf[2][2];
#pragma unroll
  for (int g=0;g<2;g++){
    const int row = q0 + qw + g*16 + l16;
#pragma unroll
    for (int dh=0;dh<2;dh++)
      qf[g][dh] = *(const s16x8*)(Q + (size_t)(nb*2048+row)*1024 + h*64 + dh*32 + quad*8);
  }
  f32x4 OT[2][4];                           // C: d = td*16+quad*4+rg, q-col = l16
  f32x4 Lacc[2];                            // ones-MFMA: all rows = sum_k P[k][q]
#pragma unroll
  for (int g=0;g<2;g++){
#pragma unroll
    for (int td=0;td<4;td++) OT[g][td] = f32x4{0.f,0.f,0.f,0.f};
    Lacc[g] = f32x4{0.f,0.f,0.f,0.f};
  }
  s16x8 ones;
#pragma unroll
  for (int j=0;j<8;j++) ones[j] = (short)0x3F80;   // bf16 1.0

  s16x8 kreg[2], vreg[2];
  auto LOADT = [&](int kn){
#pragma unroll
    for (int p=0;p<2;p++){
      const int s = p*512 + tid;
      kreg[p] = *(const s16x8*)(K + (size_t)(nb*2048+kn+(s>>3))*1024 + h*64 + (s&7)*8);
      vreg[p] = *(const s16x8*)(Vt + (size_t)((nb*16+h)*64+(s>>4))*2048 + kn + (s&15)*8);
    }
  };
  auto WRITET = [&](int b){
    u16* Ktb = KtB[b]; u16* Vtb = VtB[b];
#pragma unroll
    for (int p=0;p<2;p++){
      const int s = p*512 + tid;
      *(s16x8*)(Ktb + (s>>3)*72 + (s&7)*8) = kreg[p];
      *(s16x8*)(Vtb + (s>>4)*136 + (s&15)*8) = vreg[p];
    }
  };

  LOADT(0);
  WRITET(0);
  LOADT(128);
  __syncthreads();

  for (int t=0;t<16;t++){
    const int cur = t&1;
    if (t < 15) WRITET(cur^1);              // regs hold tile t+1; buf consumed at t-1
    if (t < 14) LOADT((t+2)*128);           // latency hides under this tile's math
    const u16* KtC = KtB[cur];
    const u16* VtC = VtB[cur];

#pragma unroll
    for (int kb=0;kb<2;kb++){               // this wave's keys: kh*64 + kb*32 + ...
      u32 ew[2][2], ow[2][2];               // packed bf16 P words [g][h]
#pragma unroll
      for (int sel=0;sel<2;sel++){
        const int key = kh*64 + kb*32 + sel*16 + l16;
        const s16x8 kf0 = *(const s16x8*)(KtC + key*72 + quad*8);
        const s16x8 kf1 = *(const s16x8*)(KtC + key*72 + 32 + quad*8);
#pragma unroll
        for (int g=0;g<2;g++){
          f32x4 z = f32x4{0.f,0.f,0.f,0.f};
          z = MFMA16(kf0, qf[g][0], z);
          z = MFMA16(kf1, qf[g][1], z);
          const float p0 = __builtin_amdgcn_exp2f(z[0]);
          const float p1 = __builtin_amdgcn_exp2f(z[1]);
          const float p2 = __builtin_amdgcn_exp2f(z[2]);
          const float p3 = __builtin_amdgcn_exp2f(z[3]);
          const u32 w0 = __builtin_amdgcn_perm(fbits(p1), fbits(p0), 0x07060302u);
          const u32 w1 = __builtin_amdgcn_perm(fbits(p3), fbits(p2), 0x07060302u);
          if (sel==0){ ew[g][0]=w0; ew[g][1]=w1; } else { ow[g][0]=w0; ow[g][1]=w1; }
        }
      }
      // in-register P redistribution via builtins (hazard-safe)
      s16x8 pf[2];
#pragma unroll
      for (int g=0;g<2;g++){
        const u32x2 r32 = __builtin_amdgcn_permlane32_swap(ew[g][0], ow[g][0], false, false);
        const u32x2 r16 = __builtin_amdgcn_permlane16_swap(r32[0], r32[1], false, false);
        const u32x2 s32 = __builtin_amdgcn_permlane32_swap(ew[g][1], ow[g][1], false, false);
        const u32x2 s16v = __builtin_amdgcn_permlane16_swap(s32[0], s32[1], false, false);
        u32x4 pw; pw[0]=r16[0]; pw[1]=s16v[0]; pw[2]=r16[1]; pw[3]=s16v[1];
        pf[g] = __builtin_bit_cast(s16x8, pw);
      }
      // OT += V^T·P^T ; l-sum via ones-MFMA (sums the SAME bf16 P as PV)
      __builtin_amdgcn_s_setprio(1);
#pragma unroll
      for (int td=0;td<4;td++){
        const s16x8 vf = *(const s16x8*)(VtC + (td*16+l16)*136 + kh*64 + kb*32 + quad*8);
#pragma unroll
        for (int g=0;g<2;g++)
          OT[g][td] = MFMA16(vf, pf[g], OT[g][td]);
      }
#pragma unroll
      for (int g=0;g<2;g++)
        Lacc[g] = MFMA16(ones, pf[g], Lacc[g]);
      __builtin_amdgcn_s_setprio(0);
    }
    __syncthreads();   // readers of buf[cur] done AND writes to buf[cur^1] visible
  }

  // epilogue: merge the two key-halves via LDS (dead K/V buffers), then pack.
  // ep: 128 q x pitch-68 f32 (34816 B <= KtB's 36864); lw: 128 f32 in VtB.
  float* ep = (float*)KtB;
  float* lw = (float*)VtB;
  if (kh==1){
#pragma unroll
    for (int g=0;g<2;g++){
      const int q = qw + g*16 + l16;
#pragma unroll
      for (int td=0;td<4;td++)
        *(f32x4*)(ep + q*68 + td*16 + quad*4) = OT[g][td];
      if (quad==0) lw[q] = Lacc[g][0];
    }
  }
  __syncthreads();
  if (kh==0){
#pragma unroll
    for (int g=0;g<2;g++){
      const int q = qw + g*16 + l16;
      const float linv = 1.0f / (Lacc[g][0] + lw[q]);
      const int qout = q0 + q;
#pragma unroll
      for (int td=0;td<4;td++){
        const f32x4 o2 = *(const f32x4*)(ep + q*68 + td*16 + quad*4);
        u16x4 pk;
#pragma unroll
        for (int rg=0;rg<4;rg++) pk[rg] = f2b((OT[g][td][rg]+o2[rg])*linv);
        *(u16x4*)(Out + (size_t)(nb*2048+qout)*1024 + h*64 + td*16 + quad*4) = pk;
      }
    }
  }
}

extern "C" void kernel_launch(void* const* d_in, const int* in_sizes, int n_in,
                              void* d_out, int out_size, void* d_ws, size_t ws_size,
                              hipStream_t stream)
{
  const float* x  = (const float*)d_in[0];
  const float* Wq = (const float*)d_in[1];  const float* bq = (const float*)d_in[2];
  const float* Aq = (const float*)d_in[3];  const float* Bq = (const float*)d_in[4];
  const float* Wk = (const float*)d_in[5];  const float* bk = (const float*)d_in[6];
  const float* Ak = (const float*)d_in[7];  const float* Bk = (const float*)d_in[8];
  const float* Wv = (const float*)d_in[9];  const float* bv = (const float*)d_in[10];
  const float* Av = (const float*)d_in[11]; const float* Bv = (const float*)d_in[12];
  const float* Wo = (const float*)d_in[13]; const float* bo = (const float*)d_in[14];
  const float* Ao = (const float*)d_in[15]; const float* Bo = (const float*)d_in[16];

  char* ws = (char*)d_ws;
  float* tq = (float*)(ws + 0);
  float* tk = (float*)(ws + 131072);
  float* tv = (float*)(ws + 262144);
  float* to = (float*)(ws + 393216);
  u16* xb  = (u16*)(ws + 524288);              // 8 MB; Ab aliases (xb dead after QKV)
  u16* Ab  = xb;
  u16* Wb  = (u16*)(ws + 524288 + 8388608);
  u16* Qb  = (u16*)(ws + 524288 + 2*8388608);
  u16* Kb  = (u16*)(ws + 524288 + 3*8388608);
  u16* Vtb = (u16*)(ws + 524288 + 4*8388608);

  lora_conv_kernel<true,3><<<dim3(2048),256,0,stream>>>(
      x, Aq, Ak, Av, tq, tk, tv, xb, Wq, Wk, Wv, Wo, Wb);
  gemm_qkv_kernel<<<dim3(24,32),256,0,stream>>>(xb, Wb, bq, bk, bv, tq, tk, tv,
                                                Bq, Bk, Bv, Qb, Kb, Vtb);
  attn_kernel<<<dim3(16,16,2),512,0,stream>>>(Qb, Kb, Vtb, Ab);
  lora_conv_kernel<false,1><<<dim3(1024),256,0,stream>>>(
      Ab, Ao, Ao, Ao, to, to, to, nullptr,
      nullptr, nullptr, nullptr, nullptr, nullptr);
  gemm_o_kernel<<<dim3(16,32),256,0,stream>>>(Ab, Wb + (size_t)3*1048576, bo, to, Bo,
                                              (float*)d_out);
}

// Round 6
// 232.227 us; speedup vs baseline: 1.2216x; 1.0274x over previous
//
#include <hip/hip_runtime.h>
#include <stdint.h>

typedef uint16_t u16;
typedef short s16x8 __attribute__((ext_vector_type(8)));
typedef float f32x4 __attribute__((ext_vector_type(4)));
typedef unsigned short u16x4 __attribute__((ext_vector_type(4)));
typedef uint32_t u32;
typedef u32 u32x2 __attribute__((ext_vector_type(2)));
typedef u32 u32x4 __attribute__((ext_vector_type(4)));

#define MFMA16(a,b,c) __builtin_amdgcn_mfma_f32_16x16x32_bf16((a),(b),(c),0,0,0)
#define QSCALE 0.18033688011112042f   // 0.125 * log2(e)

__device__ __forceinline__ float b2f(u16 b){
  union { u32 u; float f; } v; v.u = ((u32)b)<<16; return v.f;
}
__device__ __forceinline__ u16 f2b(float f){
  union { float f; u32 u; } v; v.f = f;
  return (u16)((v.u + 0x7fffu + ((v.u>>16)&1u))>>16);
}
__device__ __forceinline__ u32 fbits(float f){
  union { float f; u32 u; } v; v.f = f; return v.u;
}
__device__ __forceinline__ void load_lds_16B(const void* g, void* l){
  __builtin_amdgcn_global_load_lds((const __attribute__((address_space(1))) void*)g,
                                   (__attribute__((address_space(3))) void*)l, 16, 0, 0);
}

// ---------------- merged kernel 1: LoRA t=X@A^T (QKV) + W fp32->bf16 + zero(to)
// grid 2048. blocks [0,1024): lora rows (also emits xb bf16);
//            blocks [1024,2048): convert W0..W3 -> Wb AND zero 32 f32 of to.
__global__ __launch_bounds__(256) void lora_conv_kernel(
    const float* __restrict__ x,
    const float* __restrict__ A0, const float* __restrict__ A1, const float* __restrict__ A2,
    float* __restrict__ T0, float* __restrict__ T1, float* __restrict__ T2,
    u16* __restrict__ xb,
    const float* __restrict__ W0, const float* __restrict__ W1,
    const float* __restrict__ W2, const float* __restrict__ W3,
    u16* __restrict__ Wb, float* __restrict__ toz)
{
  if (blockIdx.x >= 1024){
    const int cv = blockIdx.x - 1024;
    if (threadIdx.x < 32) toz[cv*32 + threadIdx.x] = 0.f;   // 1024*32 = 4096*8
    const int y = cv>>8;
    const float* src = (y==0)?W0:(y==1)?W1:(y==2)?W2:W3;
    u16* dst = Wb + (size_t)y*1048576;
    const int g = (cv&255)*256 + threadIdx.x;
#pragma unroll
    for (int t=0;t<4;t++){
      const int i4 = g + t*65536;
      const f32x4 v = *(const f32x4*)(src + (size_t)i4*4);
      u16x4 o;
#pragma unroll
      for (int j=0;j<4;j++) o[j] = f2b(v[j]);
      *(u16x4*)(dst + (size_t)i4*4) = o;
    }
    return;
  }

  const int wid = threadIdx.x>>6, lane = threadIdx.x&63;
  const int m = blockIdx.x*4 + wid;

  float xf[16];
  {
    const float* xp = x + (size_t)m*1024 + lane*16;
#pragma unroll
    for (int q=0;q<4;q++){
      const f32x4 v = *(const f32x4*)(xp + q*4);
#pragma unroll
      for (int j=0;j<4;j++) xf[q*4+j] = v[j];
    }
    u16* xbp = xb + (size_t)m*1024 + lane*16;
#pragma unroll
    for (int q=0;q<4;q++){
      u16x4 o;
#pragma unroll
      for (int j=0;j<4;j++) o[j] = f2b(xf[q*4+j]);
      *(u16x4*)(xbp + q*4) = o;
    }
  }

#pragma unroll
  for (int mat=0; mat<3; mat++){
    const float* A = (mat==0)?A0:(mat==1)?A1:A2;
    float* T = (mat==0)?T0:(mat==1)?T1:T2;
    float accv[8];
#pragma unroll
    for (int r=0;r<8;r++){
      const float* ap = A + r*1024 + lane*16;
      float s = 0.f;
#pragma unroll
      for (int q=0;q<4;q++){
        const f32x4 av = *(const f32x4*)(ap + q*4);
#pragma unroll
        for (int j=0;j<4;j++) s += xf[q*4+j]*av[j];
      }
      accv[r] = s;
    }
#pragma unroll
    for (int r=0;r<8;r++){
      float s = accv[r];
      s += __shfl_xor(s,1);  s += __shfl_xor(s,2);  s += __shfl_xor(s,4);
      s += __shfl_xor(s,8);  s += __shfl_xor(s,16); s += __shfl_xor(s,32);
      accv[r] = s;
    }
    if (lane==0){
#pragma unroll
      for (int r=0;r<8;r++) T[(size_t)m*8 + r] = accv[r];
    }
  }
}

// ---------------- fused QKV GEMM, BK=64 (2x 32-wide sub-tiles per barrier) ---
// grid (24,32): proj = bx>>3 (0=Q,1=K,2=V), n0=(bx&7)*128, m0=by*128.
// Halved barrier count vs BK=32 (the m97-structure stall is the per-step
// vmcnt(0)+barrier drain). LDS 32 KB/block.
__global__ __launch_bounds__(256,2) void gemm_qkv_kernel(
    const u16* __restrict__ Xb, const u16* __restrict__ Wb,
    const float* __restrict__ bq, const float* __restrict__ bk, const float* __restrict__ bv,
    const float* __restrict__ tq, const float* __restrict__ tk, const float* __restrict__ tv,
    const float* __restrict__ Blq, const float* __restrict__ Blk, const float* __restrict__ Blv,
    u16* __restrict__ Qb, u16* __restrict__ Kb, u16* __restrict__ Vtb)
{
  __shared__ u16 At[2][128*32];
  __shared__ u16 Bt[2][128*32];
  const int tid = threadIdx.x;
  const int wid = tid>>6, lane = tid&63;
  const int quad = lane>>4, l16 = lane&15;
  const int wm = wid>>1, wn = wid&1;
  const int proj = blockIdx.x>>3;
  const int n0 = (blockIdx.x&7)<<7, m0 = blockIdx.y<<7;
  const u16* W = Wb + (size_t)proj*1048576;
  const float* bias = (proj==0)?bq:(proj==1)?bk:bv;
  const float* T    = (proj==0)?tq:(proj==1)?tk:tv;
  const float* Bl   = (proj==0)?Blq:(proj==1)?Blk:Blv;
  const float scale = (proj==0)?QSCALE:1.0f;

  f32x4 acc[4][4];
#pragma unroll
  for (int i=0;i<4;i++)
#pragma unroll
    for (int j=0;j<4;j++) acc[i][j] = f32x4{0.f,0.f,0.f,0.f};

  for (int k0=0;k0<1024;k0+=64){
#pragma unroll
    for (int half=0; half<2; half++){
#pragma unroll
      for (int p=0;p<2;p++){
        const int s = wid*128 + p*64 + lane;
        const int row = s>>2, c = s&3;
        load_lds_16B(Xb + (size_t)(m0+row)*1024 + k0 + half*32 + c*8, At[half] + (wid*128+p*64)*8);
        load_lds_16B(W  + (size_t)(n0+row)*1024 + k0 + half*32 + c*8, Bt[half] + (wid*128+p*64)*8);
      }
    }
    __syncthreads();
#pragma unroll
    for (int half=0; half<2; half++){
      s16x8 af[4], bfr[4];
#pragma unroll
      for (int t=0;t<4;t++){
        const int r = wm*64 + t*16 + l16;
        af[t]  = *(const s16x8*)(At[half] + r*32 + quad*8);
        const int c = wn*64 + t*16 + l16;
        bfr[t] = *(const s16x8*)(Bt[half] + c*32 + quad*8);
      }
#pragma unroll
      for (int tm=0;tm<4;tm++)
#pragma unroll
        for (int tn=0;tn<4;tn++)
          acc[tm][tn] = MFMA16(af[tm], bfr[tn], acc[tm][tn]);
    }
    __syncthreads();
  }

  // LoRA term via one K=8 (zero-padded to 32) MFMA per acc tile: quad0 holds k=0..7
  s16x8 tf[4], bfl[4];
#pragma unroll
  for (int t=0;t<4;t++){ tf[t] = s16x8{0,0,0,0,0,0,0,0}; bfl[t] = s16x8{0,0,0,0,0,0,0,0}; }
  if (quad==0){
#pragma unroll
    for (int tm=0;tm<4;tm++){
      const float* tp = T + (size_t)(m0 + wm*64 + tm*16 + l16)*8;
      const f32x4 a0 = *(const f32x4*)(tp);
      const f32x4 a1 = *(const f32x4*)(tp+4);
#pragma unroll
      for (int j=0;j<4;j++){ tf[tm][j] = (short)f2b(2.0f*a0[j]); tf[tm][4+j] = (short)f2b(2.0f*a1[j]); }
    }
#pragma unroll
    for (int tn=0;tn<4;tn++){
      const float* bp = Bl + (size_t)(n0 + wn*64 + tn*16 + l16)*8;
      const f32x4 b0 = *(const f32x4*)(bp);
      const f32x4 b1 = *(const f32x4*)(bp+4);
#pragma unroll
      for (int j=0;j<4;j++){ bfl[tn][j] = (short)f2b(b0[j]); bfl[tn][4+j] = (short)f2b(b1[j]); }
    }
  }
#pragma unroll
  for (int tm=0;tm<4;tm++)
#pragma unroll
    for (int tn=0;tn<4;tn++)
      acc[tm][tn] = MFMA16(tf[tm], bfl[tn], acc[tm][tn]);

#pragma unroll
  for (int tn=0;tn<4;tn++){
    const int n = n0 + wn*64 + tn*16 + l16;
    const float bn = bias[n];
#pragma unroll
    for (int tm=0;tm<4;tm++){
      const int mb = m0 + wm*64 + tm*16 + quad*4;
      if (proj==0){
#pragma unroll
        for (int rg=0;rg<4;rg++) Qb[(size_t)(mb+rg)*1024 + n] = f2b((acc[tm][tn][rg]+bn)*scale);
      } else if (proj==1){
#pragma unroll
        for (int rg=0;rg<4;rg++) Kb[(size_t)(mb+rg)*1024 + n] = f2b(acc[tm][tn][rg]+bn);
      } else {
        const int batch = mb>>11, sI = mb&2047;
        const int hh = n>>6, dd = n&63;
        u16x4 pk;
#pragma unroll
        for (int rg=0;rg<4;rg++) pk[rg] = f2b(acc[tm][tn][rg]+bn);
        *(u16x4*)(Vtb + (size_t)((batch*16+hh)*64+dd)*2048 + sI) = pk;
      }
    }
  }
}

// ---------------- O-proj GEMM: 128x64 tiles, BK=64, fp32 out, MFMA LoRA epi --
__global__ __launch_bounds__(256,2) void gemm_o_kernel(
    const u16* __restrict__ Xb, const u16* __restrict__ W,
    const float* __restrict__ bias, const float* __restrict__ T,
    const float* __restrict__ Bl, float* __restrict__ Out)
{
  __shared__ u16 At[2][128*32];
  __shared__ u16 Bt[2][64*32];
  const int tid = threadIdx.x;
  const int wid = tid>>6, lane = tid&63;
  const int quad = lane>>4, l16 = lane&15;
  const int wm = wid>>1, wn = wid&1;
  const int m0 = blockIdx.y<<7, n0 = blockIdx.x<<6;

  f32x4 acc[4][2];
#pragma unroll
  for (int i=0;i<4;i++)
#pragma unroll
    for (int j=0;j<2;j++) acc[i][j] = f32x4{0.f,0.f,0.f,0.f};

  for (int k0=0;k0<1024;k0+=64){
#pragma unroll
    for (int half=0; half<2; half++){
#pragma unroll
      for (int p=0;p<2;p++){
        const int s = wid*128 + p*64 + lane;
        const int row = s>>2, c = s&3;
        load_lds_16B(Xb + (size_t)(m0+row)*1024 + k0 + half*32 + c*8, At[half] + (wid*128+p*64)*8);
      }
      { const int s = wid*64 + lane;
        const int row = s>>2, c = s&3;
        load_lds_16B(W + (size_t)(n0+row)*1024 + k0 + half*32 + c*8, Bt[half] + (wid*64)*8); }
    }
    __syncthreads();
#pragma unroll
    for (int half=0; half<2; half++){
      s16x8 af[4], bfr[2];
#pragma unroll
      for (int t=0;t<4;t++){
        const int r = wm*64 + t*16 + l16;
        af[t] = *(const s16x8*)(At[half] + r*32 + quad*8);
      }
#pragma unroll
      for (int t=0;t<2;t++){
        const int c = wn*32 + t*16 + l16;
        bfr[t] = *(const s16x8*)(Bt[half] + c*32 + quad*8);
      }
#pragma unroll
      for (int tm=0;tm<4;tm++)
#pragma unroll
        for (int tn=0;tn<2;tn++)
          acc[tm][tn] = MFMA16(af[tm], bfr[tn], acc[tm][tn]);
    }
    __syncthreads();
  }

  s16x8 tf[4], bfl[2];
#pragma unroll
  for (int t=0;t<4;t++) tf[t] = s16x8{0,0,0,0,0,0,0,0};
#pragma unroll
  for (int t=0;t<2;t++) bfl[t] = s16x8{0,0,0,0,0,0,0,0};
  if (quad==0){
#pragma unroll
    for (int tm=0;tm<4;tm++){
      const float* tp = T + (size_t)(m0 + wm*64 + tm*16 + l16)*8;
      const f32x4 a0 = *(const f32x4*)(tp);
      const f32x4 a1 = *(const f32x4*)(tp+4);
#pragma unroll
      for (int j=0;j<4;j++){ tf[tm][j] = (short)f2b(2.0f*a0[j]); tf[tm][4+j] = (short)f2b(2.0f*a1[j]); }
    }
#pragma unroll
    for (int tn=0;tn<2;tn++){
      const float* bp = Bl + (size_t)(n0 + wn*32 + tn*16 + l16)*8;
      const f32x4 b0 = *(const f32x4*)(bp);
      const f32x4 b1 = *(const f32x4*)(bp+4);
#pragma unroll
      for (int j=0;j<4;j++){ bfl[tn][j] = (short)f2b(b0[j]); bfl[tn][4+j] = (short)f2b(b1[j]); }
    }
  }
#pragma unroll
  for (int tm=0;tm<4;tm++)
#pragma unroll
    for (int tn=0;tn<2;tn++)
      acc[tm][tn] = MFMA16(tf[tm], bfl[tn], acc[tm][tn]);

#pragma unroll
  for (int tn=0;tn<2;tn++){
    const int n = n0 + wn*32 + tn*16 + l16;
    const float bn = bias[n];
#pragma unroll
    for (int tm=0;tm<4;tm++){
      const int mb = m0 + wm*64 + tm*16 + quad*4;
#pragma unroll
      for (int rg=0;rg<4;rg++)
        Out[(size_t)(mb+rg)*1024 + n] = acc[tm][tn][rg] + bn;
    }
  }
}

// ---------------- MFMA flash attention v6 ------------------------------------
// v5 core (split-K waves, ones-MFMA l-sum, permlane P redistribution,
// double-buffered K/V, one barrier/tile) + FUSED LoRA-o partial:
// epilogue computes to[m][r] += sum_{d in head} O_bf16[m][d]*Ao[r][d] via
// per-thread 16-elem dots + quad shfl-reduce + one atomicAdd per (q,r).
// Replaces the separate lora pass (8.4 MB re-read + launch gap). to is zeroed
// by kernel 1; f32 atomic ordering noise ~1e-6 << 1.27e-3 threshold.
__global__ __launch_bounds__(512,4) void attn_kernel(
    const u16* __restrict__ Q, const u16* __restrict__ K,
    const u16* __restrict__ Vt, u16* __restrict__ Out,
    const float* __restrict__ Ao, float* __restrict__ to)
{
  __shared__ u16 KtB[2][128*72];
  __shared__ u16 VtB[2][64*136];
  const int tid = threadIdx.x;
  const int wid = tid>>6, lane = tid&63;
  const int quad = lane>>4, l16 = lane&15;
  const int q0 = blockIdx.x<<7;
  const int h = blockIdx.y, nb = blockIdx.z;
  const int qg = wid>>1;                    // q-group 0..3: 32 q-cols
  const int kh = wid&1;                     // key-half 0..1: 64 keys/tile
  const int qw = qg*32;                     // q-cols: qw + g*16 + l16

  s16x8 qf[2][2];
#pragma unroll
  for (int g=0;g<2;g++){
    const int row = q0 + qw + g*16 + l16;
#pragma unroll
    for (int dh=0;dh<2;dh++)
      qf[g][dh] = *(const s16x8*)(Q + (size_t)(nb*2048+row)*1024 + h*64 + dh*32 + quad*8);
  }
  f32x4 OT[2][4];                           // C: d = td*16+quad*4+rg, q-col = l16
  f32x4 Lacc[2];                            // ones-MFMA: all rows = sum_k P[k][q]
#pragma unroll
  for (int g=0;g<2;g++){
#pragma unroll
    for (int td=0;td<4;td++) OT[g][td] = f32x4{0.f,0.f,0.f,0.f};
    Lacc[g] = f32x4{0.f,0.f,0.f,0.f};
  }
  s16x8 ones;
#pragma unroll
  for (int j=0;j<8;j++) ones[j] = (short)0x3F80;   // bf16 1.0

  s16x8 kreg[2], vreg[2];
  auto LOADT = [&](int kn){
#pragma unroll
    for (int p=0;p<2;p++){
      const int s = p*512 + tid;
      kreg[p] = *(const s16x8*)(K + (size_t)(nb*2048+kn+(s>>3))*1024 + h*64 + (s&7)*8);
      vreg[p] = *(const s16x8*)(Vt + (size_t)((nb*16+h)*64+(s>>4))*2048 + kn + (s&15)*8);
    }
  };
  auto WRITET = [&](int b){
    u16* Ktb = KtB[b]; u16* Vtb = VtB[b];
#pragma unroll
    for (int p=0;p<2;p++){
      const int s = p*512 + tid;
      *(s16x8*)(Ktb + (s>>3)*72 + (s&7)*8) = kreg[p];
      *(s16x8*)(Vtb + (s>>4)*136 + (s&15)*8) = vreg[p];
    }
  };

  LOADT(0);
  WRITET(0);
  LOADT(128);
  __syncthreads();

  for (int t=0;t<16;t++){
    const int cur = t&1;
    if (t < 15) WRITET(cur^1);              // regs hold tile t+1; buf consumed at t-1
    if (t < 14) LOADT((t+2)*128);           // latency hides under this tile's math
    const u16* KtC = KtB[cur];
    const u16* VtC = VtB[cur];

#pragma unroll
    for (int kb=0;kb<2;kb++){               // this wave's keys: kh*64 + kb*32 + ...
      u32 ew[2][2], ow[2][2];               // packed bf16 P words [g][h]
#pragma unroll
      for (int sel=0;sel<2;sel++){
        const int key = kh*64 + kb*32 + sel*16 + l16;
        const s16x8 kf0 = *(const s16x8*)(KtC + key*72 + quad*8);
        const s16x8 kf1 = *(const s16x8*)(KtC + key*72 + 32 + quad*8);
#pragma unroll
        for (int g=0;g<2;g++){
          f32x4 z = f32x4{0.f,0.f,0.f,0.f};
          z = MFMA16(kf0, qf[g][0], z);
          z = MFMA16(kf1, qf[g][1], z);
          const float p0 = __builtin_amdgcn_exp2f(z[0]);
          const float p1 = __builtin_amdgcn_exp2f(z[1]);
          const float p2 = __builtin_amdgcn_exp2f(z[2]);
          const float p3 = __builtin_amdgcn_exp2f(z[3]);
          const u32 w0 = __builtin_amdgcn_perm(fbits(p1), fbits(p0), 0x07060302u);
          const u32 w1 = __builtin_amdgcn_perm(fbits(p3), fbits(p2), 0x07060302u);
          if (sel==0){ ew[g][0]=w0; ew[g][1]=w1; } else { ow[g][0]=w0; ow[g][1]=w1; }
        }
      }
      // in-register P redistribution via builtins (hazard-safe)
      s16x8 pf[2];
#pragma unroll
      for (int g=0;g<2;g++){
        const u32x2 r32 = __builtin_amdgcn_permlane32_swap(ew[g][0], ow[g][0], false, false);
        const u32x2 r16 = __builtin_amdgcn_permlane16_swap(r32[0], r32[1], false, false);
        const u32x2 s32 = __builtin_amdgcn_permlane32_swap(ew[g][1], ow[g][1], false, false);
        const u32x2 s16v = __builtin_amdgcn_permlane16_swap(s32[0], s32[1], false, false);
        u32x4 pw; pw[0]=r16[0]; pw[1]=s16v[0]; pw[2]=r16[1]; pw[3]=s16v[1];
        pf[g] = __builtin_bit_cast(s16x8, pw);
      }
      // OT += V^T·P^T ; l-sum via ones-MFMA (sums the SAME bf16 P as PV)
      __builtin_amdgcn_s_setprio(1);
#pragma unroll
      for (int td=0;td<4;td++){
        const s16x8 vf = *(const s16x8*)(VtC + (td*16+l16)*136 + kh*64 + kb*32 + quad*8);
#pragma unroll
        for (int g=0;g<2;g++)
          OT[g][td] = MFMA16(vf, pf[g], OT[g][td]);
      }
#pragma unroll
      for (int g=0;g<2;g++)
        Lacc[g] = MFMA16(ones, pf[g], Lacc[g]);
      __builtin_amdgcn_s_setprio(0);
    }
    __syncthreads();   // readers of buf[cur] done AND writes to buf[cur^1] visible
  }

  // epilogue: merge the two key-halves via LDS (dead K/V buffers), pack, and
  // accumulate the fused LoRA-o partial t.
  float* ep = (float*)KtB;
  float* lw = (float*)VtB;
  if (kh==1){
#pragma unroll
    for (int g=0;g<2;g++){
      const int q = qw + g*16 + l16;
#pragma unroll
      for (int td=0;td<4;td++)
        *(f32x4*)(ep + q*68 + td*16 + quad*4) = OT[g][td];
      if (quad==0) lw[q] = Lacc[g][0];
    }
  }
  __syncthreads();
  if (kh==0){
#pragma unroll
    for (int g=0;g<2;g++){
      const int q = qw + g*16 + l16;
      const float linv = 1.0f / (Lacc[g][0] + lw[q]);
      const int qout = q0 + q;
      float obf[4][4];
#pragma unroll
      for (int td=0;td<4;td++){
        const f32x4 o2 = *(const f32x4*)(ep + q*68 + td*16 + quad*4);
        u16x4 pk;
#pragma unroll
        for (int rg=0;rg<4;rg++){
          pk[rg] = f2b((OT[g][td][rg]+o2[rg])*linv);
          obf[td][rg] = b2f(pk[rg]);
        }
        *(u16x4*)(Out + (size_t)(nb*2048+qout)*1024 + h*64 + td*16 + quad*4) = pk;
      }
      // to[m][r] += sum over this thread's 16 d of obf*Ao[r][h*64+d];
      // 4 quads cover d=0..63 of this head -> shfl-reduce then one atomic.
#pragma unroll
      for (int r=0;r<8;r++){
        float s = 0.f;
#pragma unroll
        for (int td=0;td<4;td++){
          const f32x4 av = *(const f32x4*)(Ao + r*1024 + h*64 + td*16 + quad*4);
#pragma unroll
          for (int rg=0;rg<4;rg++) s += obf[td][rg]*av[rg];
        }
        s += __shfl_xor(s,16);
        s += __shfl_xor(s,32);
        if (quad==0) atomicAdd(to + (size_t)(nb*2048+qout)*8 + r, s);
      }
    }
  }
}

extern "C" void kernel_launch(void* const* d_in, const int* in_sizes, int n_in,
                              void* d_out, int out_size, void* d_ws, size_t ws_size,
                              hipStream_t stream)
{
  const float* x  = (const float*)d_in[0];
  const float* Wq = (const float*)d_in[1];  const float* bq = (const float*)d_in[2];
  const float* Aq = (const float*)d_in[3];  const float* Bq = (const float*)d_in[4];
  const float* Wk = (const float*)d_in[5];  const float* bk = (const float*)d_in[6];
  const float* Ak = (const float*)d_in[7];  const float* Bk = (const float*)d_in[8];
  const float* Wv = (const float*)d_in[9];  const float* bv = (const float*)d_in[10];
  const float* Av = (const float*)d_in[11]; const float* Bv = (const float*)d_in[12];
  const float* Wo = (const float*)d_in[13]; const float* bo = (const float*)d_in[14];
  const float* Ao = (const float*)d_in[15]; const float* Bo = (const float*)d_in[16];

  char* ws = (char*)d_ws;
  float* tq = (float*)(ws + 0);
  float* tk = (float*)(ws + 131072);
  float* tv = (float*)(ws + 262144);
  float* to = (float*)(ws + 393216);
  u16* xb  = (u16*)(ws + 524288);              // 8 MB; Ab aliases (xb dead after QKV)
  u16* Ab  = xb;
  u16* Wb  = (u16*)(ws + 524288 + 8388608);
  u16* Qb  = (u16*)(ws + 524288 + 2*8388608);
  u16* Kb  = (u16*)(ws + 524288 + 3*8388608);
  u16* Vtb = (u16*)(ws + 524288 + 4*8388608);

  lora_conv_kernel<<<dim3(2048),256,0,stream>>>(
      x, Aq, Ak, Av, tq, tk, tv, xb, Wq, Wk, Wv, Wo, Wb, to);
  gemm_qkv_kernel<<<dim3(24,32),256,0,stream>>>(xb, Wb, bq, bk, bv, tq, tk, tv,
                                                Bq, Bk, Bv, Qb, Kb, Vtb);
  attn_kernel<<<dim3(16,16,2),512,0,stream>>>(Qb, Kb, Vtb, Ab, Ao, to);
  gemm_o_kernel<<<dim3(16,32),256,0,stream>>>(Ab, Wb + (size_t)3*1048576, bo, to, Bo,
                                              (float*)d_out);
}